// Round 5
// baseline (1949.469 us; speedup 1.0000x reference)
//
#include <hip/hip_runtime.h>
#include <math.h>

#define N_NODES 50000
#define N_EDGES 800000
#define E_TOT   (N_EDGES + N_NODES)   // edges + self-loops = 850000
#define F_IN    256
#define NHEAD   8
#define CH      32
#define HC      256                   // NHEAD*CH
#define OUT_C   40
#define NEG_SLOPE 0.2f

// ================= GEMM1: h1[N,256] = x[N,256] @ W1[256,256] (fp32)
// Block: 32 rows x 256 cols. Thread: 8 rows x 4 cols -> acc[8] float4 = 32 VGPRs.
// launch_bounds(256,4) caps VGPRs at 128 (round-4 spilled at 256: WRITE_SIZE 1.15GB).
#define G1_TR 32
#define G1_TK 64
__global__ __launch_bounds__(256, 4) void gemm1_kernel(const float* __restrict__ x,
        const float* __restrict__ W, float* __restrict__ h1) {
    __shared__ float4 xs[G1_TR][G1_TK / 4];    // 32 x 16 float4 = 8 KB
    const int row0 = blockIdx.x * G1_TR;
    const int t    = threadIdx.x;
    const int lane = t & 63;       // col group: cols lane*4 .. lane*4+3
    const int wrow = t >> 6;       // wave id 0..3 -> rows wrow*8 .. +7
    const float4* W4 = (const float4*)W;   // W4[k*64 + lane] = W[k][lane*4..+3]

    float4 acc[8];
    #pragma unroll
    for (int i = 0; i < 8; ++i) acc[i] = make_float4(0.f, 0.f, 0.f, 0.f);

    #pragma unroll 1
    for (int kt = 0; kt < F_IN; kt += G1_TK) {
        __syncthreads();
        // stage x tile: 32 rows x 64 k (512 float4, 2 per thread)
        for (int i = t; i < G1_TR * (G1_TK / 4); i += 256) {
            int r  = i >> 4;
            int k4 = i & 15;
            int gr = row0 + r;
            float4 v = make_float4(0.f, 0.f, 0.f, 0.f);
            if (gr < N_NODES) v = ((const float4*)(x + (size_t)gr * F_IN + kt))[k4];
            xs[r][k4] = v;
        }
        __syncthreads();
        #pragma unroll
        for (int k4 = 0; k4 < G1_TK / 4; ++k4) {
            int kbase = kt + k4 * 4;
            float4 w0 = W4[(kbase + 0) * 64 + lane];
            float4 w1 = W4[(kbase + 1) * 64 + lane];
            float4 w2 = W4[(kbase + 2) * 64 + lane];
            float4 w3 = W4[(kbase + 3) * 64 + lane];
            #pragma unroll
            for (int i = 0; i < 8; ++i) {
                float4 xv = xs[wrow * 8 + i][k4];   // wave-uniform -> LDS broadcast
                acc[i].x += xv.x * w0.x + xv.y * w1.x + xv.z * w2.x + xv.w * w3.x;
                acc[i].y += xv.x * w0.y + xv.y * w1.y + xv.z * w2.y + xv.w * w3.y;
                acc[i].z += xv.x * w0.z + xv.y * w1.z + xv.z * w2.z + xv.w * w3.z;
                acc[i].w += xv.x * w0.w + xv.y * w1.w + xv.z * w2.w + xv.w * w3.w;
            }
        }
    }
    #pragma unroll
    for (int i = 0; i < 8; ++i) {
        int gr = row0 + wrow * 8 + i;
        if (gr < N_NODES)
            ((float4*)(h1 + (size_t)gr * HC))[lane] = acc[i];
    }
}

// ================= GEMM2: h2[N,256] = hm[N,32] @ W2[32,256]; W2 in registers
#define G2_ROWS 128
__global__ __launch_bounds__(256) void gemm2_kernel(const float* __restrict__ hm,
        const float* __restrict__ W, float* __restrict__ h2) {
    const int row0 = blockIdx.x * G2_ROWS;
    const int c = threadIdx.x;
    float w[CH];
    #pragma unroll
    for (int k = 0; k < CH; ++k) w[k] = W[k * HC + c];
    for (int i = 0; i < G2_ROWS; ++i) {
        int row = row0 + i;
        if (row >= N_NODES) break;
        const float* hr = hm + (size_t)row * CH;   // block-uniform -> scalar loads
        float a = 0.f;
        #pragma unroll
        for (int k = 0; k < CH; ++k) a += hr[k] * w[k];
        h2[(size_t)row * HC + c] = a;
    }
}

// ================= per-node attention coefficients: asrc/adst [N,8]
__global__ __launch_bounds__(256) void alpha_kernel(const float* __restrict__ h,
        const float* __restrict__ a_src, const float* __restrict__ a_dst,
        float* __restrict__ asrc, float* __restrict__ adst) {
    int t = blockIdx.x * 256 + threadIdx.x;
    if (t >= N_NODES * NHEAD) return;
    int node = t >> 3;
    int hd   = t & 7;
    const float4* hp = (const float4*)(h + (size_t)node * HC + hd * CH);
    const float4* ap = (const float4*)(a_src + hd * CH);
    const float4* dp = (const float4*)(a_dst + hd * CH);
    float s1 = 0.f, s2 = 0.f;
    #pragma unroll
    for (int i = 0; i < CH / 4; ++i) {
        float4 hv = hp[i], av = ap[i], dv = dp[i];
        s1 += hv.x * av.x + hv.y * av.y + hv.z * av.z + hv.w * av.w;
        s2 += hv.x * dv.x + hv.y * dv.y + hv.z * dv.z + hv.w * dv.w;
    }
    asrc[t] = s1;
    adst[t] = s2;
}

// ================= CSR build =================
__global__ __launch_bounds__(256) void deg_kernel(const int* __restrict__ ei,
        int* __restrict__ deg) {
    int j = blockIdx.x * 256 + threadIdx.x;
    if (j >= E_TOT) return;
    int dst = (j < N_EDGES) ? ei[N_EDGES + j] : (j - N_EDGES);
    atomicAdd(&deg[dst], 1);
}

// single-block exclusive scan of deg[50000] -> rowptr[50001]; cursor = copy
__global__ __launch_bounds__(1024) void scan_kernel(const int* __restrict__ deg,
        int* __restrict__ rowptr, int* __restrict__ cursor) {
    __shared__ int part[1024];
    const int t = threadIdx.x;
    const int CHK = (N_NODES + 1023) / 1024;   // 49
    const int base = t * CHK;
    int s = 0;
    for (int i = 0; i < CHK; ++i) {
        int idx = base + i;
        if (idx < N_NODES) s += deg[idx];
    }
    part[t] = s;
    __syncthreads();
    for (int off = 1; off < 1024; off <<= 1) {
        int v = (t >= off) ? part[t - off] : 0;
        __syncthreads();
        part[t] += v;
        __syncthreads();
    }
    int run = (t == 0) ? 0 : part[t - 1];
    for (int i = 0; i < CHK; ++i) {
        int idx = base + i;
        if (idx < N_NODES) {
            rowptr[idx] = run;
            cursor[idx] = run;
            run += deg[idx];
        }
    }
    if (t == 0) rowptr[N_NODES] = E_TOT;
}

__global__ __launch_bounds__(256) void scatter_kernel(const int* __restrict__ ei,
        int* __restrict__ cursor, int* __restrict__ csr_src) {
    int j = blockIdx.x * 256 + threadIdx.x;
    if (j >= E_TOT) return;
    int src, dst;
    if (j < N_EDGES) { src = ei[j]; dst = ei[N_EDGES + j]; }
    else             { src = j - N_EDGES; dst = src; }
    int pos = atomicAdd(&cursor[dst], 1);
    csr_src[pos] = src;
}

// ================= softmax denominators (gather, no atomics)
// thread = (dst, head); writes ew in CSR order and sinv = 1/(8*sum)
__global__ __launch_bounds__(256) void denom_kernel(const int* __restrict__ rowptr,
        const int* __restrict__ csr_src, const float* __restrict__ asrc,
        const float* __restrict__ adst, float* __restrict__ ew,
        float* __restrict__ sinv) {
    int t = blockIdx.x * 256 + threadIdx.x;
    if (t >= N_NODES * NHEAD) return;
    int dst = t >> 3;
    int hd  = t & 7;
    float ad = adst[t];
    int p0 = rowptr[dst], p1 = rowptr[dst + 1];
    float sum = 0.f;
    for (int p = p0; p < p1; ++p) {
        int src = csr_src[p];
        float e = asrc[src * NHEAD + hd] + ad;
        e = e > 0.f ? e : NEG_SLOPE * e;
        float ex = __expf(e);
        ew[(size_t)p * NHEAD + hd] = ex;
        sum += ex;
    }
    sinv[t] = 1.0f / (8.0f * sum);
}

// ================= aggregation (gather, no atomics) + bias + ELU
// thread = (dst, channel)
__global__ __launch_bounds__(256) void aggregate_kernel(const int* __restrict__ rowptr,
        const int* __restrict__ csr_src, const float* __restrict__ ew,
        const float* __restrict__ sinv, const float* __restrict__ h,
        const float* __restrict__ b, float* __restrict__ out) {
    int t = blockIdx.x * 256 + threadIdx.x;
    if (t >= N_NODES * CH) return;
    int dst = t >> 5;
    int c   = t & 31;
    int p0 = rowptr[dst], p1 = rowptr[dst + 1];
    float acc[NHEAD];
    #pragma unroll
    for (int hd = 0; hd < NHEAD; ++hd) acc[hd] = 0.f;
    for (int p = p0; p < p1; ++p) {
        int src = csr_src[p];                       // broadcast across 32 lanes
        const float*  hp = h + (size_t)src * HC + c;
        const float4* wp = (const float4*)(ew + (size_t)p * NHEAD);
        float4 w0 = wp[0], w1 = wp[1];
        acc[0] += w0.x * hp[0 * CH];
        acc[1] += w0.y * hp[1 * CH];
        acc[2] += w0.z * hp[2 * CH];
        acc[3] += w0.w * hp[3 * CH];
        acc[4] += w1.x * hp[4 * CH];
        acc[5] += w1.y * hp[5 * CH];
        acc[6] += w1.z * hp[6 * CH];
        acc[7] += w1.w * hp[7 * CH];
    }
    const float* sp = sinv + (size_t)dst * NHEAD;
    float val = 0.f;
    #pragma unroll
    for (int hd = 0; hd < NHEAD; ++hd) val += sp[hd] * acc[hd];
    val += b[c];
    out[t] = val > 0.f ? val : (__expf(val) - 1.f);
}

// ================= output head: logits = h@Wo + bo, log_softmax (1 wave/node)
__global__ __launch_bounds__(64) void out_kernel(const float* __restrict__ hf,
        const float* __restrict__ Wo, const float* __restrict__ bo,
        float* __restrict__ out) {
    const int n = blockIdx.x;
    const int lane = threadIdx.x;
    __shared__ float hs[CH];
    if (lane < CH) hs[lane] = hf[n * CH + lane];
    __syncthreads();
    float logit = -INFINITY;
    if (lane < OUT_C) {
        float a = bo[lane];
        #pragma unroll
        for (int k = 0; k < CH; ++k) a += hs[k] * Wo[k * OUT_C + lane];
        logit = a;
    }
    float m = logit;
    #pragma unroll
    for (int off = 32; off; off >>= 1) m = fmaxf(m, __shfl_xor(m, off, 64));
    float ex = (lane < OUT_C) ? __expf(logit - m) : 0.f;
    float ssum = ex;
    #pragma unroll
    for (int off = 32; off; off >>= 1) ssum += __shfl_xor(ssum, off, 64);
    if (lane < OUT_C) out[(size_t)n * OUT_C + lane] = logit - m - __logf(ssum);
}

extern "C" void kernel_launch(void* const* d_in, const int* in_sizes, int n_in,
                              void* d_out, int out_size, void* d_ws, size_t ws_size,
                              hipStream_t stream) {
    const float* x      = (const float*)d_in[0];
    const int*   ei     = (const int*)  d_in[1];
    const float* W1     = (const float*)d_in[2];
    const float* a_src1 = (const float*)d_in[3];
    const float* a_dst1 = (const float*)d_in[4];
    const float* b1     = (const float*)d_in[5];
    const float* W2     = (const float*)d_in[6];
    const float* a_src2 = (const float*)d_in[7];
    const float* a_dst2 = (const float*)d_in[8];
    const float* b2     = (const float*)d_in[9];
    const float* Wo     = (const float*)d_in[10];
    const float* bo     = (const float*)d_in[11];
    float* out = (float*)d_out;

    // workspace carve-up (256B-aligned)
    char* ws = (char*)d_ws;
    size_t off = 0;
    auto carve = [&](size_t bytes) { char* p = ws + off; off += (bytes + 255) & ~(size_t)255; return p; };
    float* h_big   = (float*)carve((size_t)N_NODES * HC * 4);      // 51.2 MB
    float* asrc    = (float*)carve((size_t)N_NODES * NHEAD * 4);   // 1.6 MB
    float* adst    = (float*)carve((size_t)N_NODES * NHEAD * 4);
    float* sinv    = (float*)carve((size_t)N_NODES * NHEAD * 4);
    float* ew      = (float*)carve((size_t)E_TOT * NHEAD * 4);     // 27.2 MB
    float* hmid    = (float*)carve((size_t)N_NODES * CH * 4);      // 6.4 MB
    float* hout    = (float*)carve((size_t)N_NODES * CH * 4);      // 6.4 MB
    int*   deg     = (int*)  carve((size_t)N_NODES * 4);
    int*   rowptr  = (int*)  carve((size_t)(N_NODES + 1) * 4);
    int*   cursor  = (int*)  carve((size_t)N_NODES * 4);
    int*   csr_src = (int*)  carve((size_t)E_TOT * 4);             // 3.4 MB

    const int g_gemm1 = (N_NODES + G1_TR - 1) / G1_TR;       // 1563
    const int g_gemm2 = (N_NODES + G2_ROWS - 1) / G2_ROWS;   // 391
    const int g_nh    = (N_NODES * NHEAD + 255) / 256;       // 1563
    const int g_edge  = (E_TOT + 255) / 256;                 // 3321
    const int g_aggr  = (N_NODES * CH + 255) / 256;          // 6250

    // ---------- CSR build (shared by both layers) ----------
    hipMemsetAsync(deg, 0, (size_t)N_NODES * 4, stream);
    deg_kernel<<<g_edge, 256, 0, stream>>>(ei, deg);
    scan_kernel<<<1, 1024, 0, stream>>>(deg, rowptr, cursor);
    scatter_kernel<<<g_edge, 256, 0, stream>>>(ei, cursor, csr_src);

    // ---------- layer 1 ----------
    gemm1_kernel<<<g_gemm1, 256, 0, stream>>>(x, W1, h_big);
    alpha_kernel<<<g_nh, 256, 0, stream>>>(h_big, a_src1, a_dst1, asrc, adst);
    denom_kernel<<<g_nh, 256, 0, stream>>>(rowptr, csr_src, asrc, adst, ew, sinv);
    aggregate_kernel<<<g_aggr, 256, 0, stream>>>(rowptr, csr_src, ew, sinv, h_big, b1, hmid);

    // ---------- layer 2 ----------
    gemm2_kernel<<<g_gemm2, 256, 0, stream>>>(hmid, W2, h_big);
    alpha_kernel<<<g_nh, 256, 0, stream>>>(h_big, a_src2, a_dst2, asrc, adst);
    denom_kernel<<<g_nh, 256, 0, stream>>>(rowptr, csr_src, asrc, adst, ew, sinv);
    aggregate_kernel<<<g_aggr, 256, 0, stream>>>(rowptr, csr_src, ew, sinv, h_big, b2, hout);

    // ---------- output head ----------
    out_kernel<<<N_NODES, 64, 0, stream>>>(hout, Wo, bo, out);
}

// Round 6
// 933.776 us; speedup vs baseline: 2.0877x; 2.0877x over previous
//
#include <hip/hip_runtime.h>
#include <math.h>

#define N_NODES 50000
#define N_EDGES 800000
#define E_TOT   (N_EDGES + N_NODES)   // edges + self-loops = 850000
#define F_IN    256
#define NHEAD   8
#define CH      32
#define HC      256                   // NHEAD*CH
#define OUT_C   40
#define NEG_SLOPE 0.2f

// ================= GEMM1: h1[N,256] = x[N,256] @ W1[256,256] (fp32)
// Block: 32 rows x 256 cols. Thread: 8 rows x 4 cols -> acc[8] float4 = 32 VGPRs.
// NOTE register history: r4 (no cap, acc[16]x4) -> compiler wanted ~320, spilled
// at 256 (WRITE 1.15GB). r5 (cap 64 via launch_bounds(256,4)) -> demand ~90,
// spilled under cap (WRITE 2.25GB). Fix: right-size tile AND no wave-count cap.
#define G1_TR 32
#define G1_TK 64
__global__ __launch_bounds__(256) void gemm1_kernel(const float* __restrict__ x,
        const float* __restrict__ W, float* __restrict__ h1) {
    __shared__ float4 xs[G1_TR][G1_TK / 4];    // 32 x 16 float4 = 8 KB
    const int row0 = blockIdx.x * G1_TR;
    const int t    = threadIdx.x;
    const int lane = t & 63;       // col group: cols lane*4 .. lane*4+3
    const int wrow = t >> 6;       // wave id 0..3 -> rows wrow*8 .. +7
    const float4* W4 = (const float4*)W;   // W4[k*64 + lane] = W[k][lane*4..+3]

    float4 acc[8];
    #pragma unroll
    for (int i = 0; i < 8; ++i) acc[i] = make_float4(0.f, 0.f, 0.f, 0.f);

    #pragma unroll 1
    for (int kt = 0; kt < F_IN; kt += G1_TK) {
        __syncthreads();
        // stage x tile: 32 rows x 64 k (512 float4, 2 per thread)
        for (int i = t; i < G1_TR * (G1_TK / 4); i += 256) {
            int r  = i >> 4;
            int k4 = i & 15;
            int gr = row0 + r;
            float4 v = make_float4(0.f, 0.f, 0.f, 0.f);
            if (gr < N_NODES) v = ((const float4*)(x + (size_t)gr * F_IN + kt))[k4];
            xs[r][k4] = v;
        }
        __syncthreads();
        #pragma unroll
        for (int k4 = 0; k4 < G1_TK / 4; ++k4) {
            int kbase = kt + k4 * 4;
            float4 w0 = W4[(kbase + 0) * 64 + lane];
            float4 w1 = W4[(kbase + 1) * 64 + lane];
            float4 w2 = W4[(kbase + 2) * 64 + lane];
            float4 w3 = W4[(kbase + 3) * 64 + lane];
            #pragma unroll
            for (int i = 0; i < 8; ++i) {
                float4 xv = xs[wrow * 8 + i][k4];   // wave-uniform -> LDS broadcast
                acc[i].x += xv.x * w0.x + xv.y * w1.x + xv.z * w2.x + xv.w * w3.x;
                acc[i].y += xv.x * w0.y + xv.y * w1.y + xv.z * w2.y + xv.w * w3.y;
                acc[i].z += xv.x * w0.z + xv.y * w1.z + xv.z * w2.z + xv.w * w3.z;
                acc[i].w += xv.x * w0.w + xv.y * w1.w + xv.z * w2.w + xv.w * w3.w;
            }
        }
    }
    #pragma unroll
    for (int i = 0; i < 8; ++i) {
        int gr = row0 + wrow * 8 + i;
        if (gr < N_NODES)
            ((float4*)(h1 + (size_t)gr * HC))[lane] = acc[i];
    }
}

// ================= GEMM2: h2[N,256] = hm[N,32] @ W2[32,256]; W2 in registers
#define G2_ROWS 128
__global__ __launch_bounds__(256) void gemm2_kernel(const float* __restrict__ hm,
        const float* __restrict__ W, float* __restrict__ h2) {
    const int row0 = blockIdx.x * G2_ROWS;
    const int c = threadIdx.x;
    float w[CH];
    #pragma unroll
    for (int k = 0; k < CH; ++k) w[k] = W[k * HC + c];
    for (int i = 0; i < G2_ROWS; ++i) {
        int row = row0 + i;
        if (row >= N_NODES) break;
        const float* hr = hm + (size_t)row * CH;   // block-uniform -> scalar loads
        float a = 0.f;
        #pragma unroll
        for (int k = 0; k < CH; ++k) a += hr[k] * w[k];
        h2[(size_t)row * HC + c] = a;
    }
}

// ================= per-node attention coefficients: asrc/adst [N,8]
__global__ __launch_bounds__(256) void alpha_kernel(const float* __restrict__ h,
        const float* __restrict__ a_src, const float* __restrict__ a_dst,
        float* __restrict__ asrc, float* __restrict__ adst) {
    int t = blockIdx.x * 256 + threadIdx.x;
    if (t >= N_NODES * NHEAD) return;
    int node = t >> 3;
    int hd   = t & 7;
    const float4* hp = (const float4*)(h + (size_t)node * HC + hd * CH);
    const float4* ap = (const float4*)(a_src + hd * CH);
    const float4* dp = (const float4*)(a_dst + hd * CH);
    float s1 = 0.f, s2 = 0.f;
    #pragma unroll
    for (int i = 0; i < CH / 4; ++i) {
        float4 hv = hp[i], av = ap[i], dv = dp[i];
        s1 += hv.x * av.x + hv.y * av.y + hv.z * av.z + hv.w * av.w;
        s2 += hv.x * dv.x + hv.y * dv.y + hv.z * dv.z + hv.w * dv.w;
    }
    asrc[t] = s1;
    adst[t] = s2;
}

// ================= CSR build =================
__global__ __launch_bounds__(256) void deg_kernel(const int* __restrict__ ei,
        int* __restrict__ deg) {
    int j = blockIdx.x * 256 + threadIdx.x;
    if (j >= E_TOT) return;
    int dst = (j < N_EDGES) ? ei[N_EDGES + j] : (j - N_EDGES);
    atomicAdd(&deg[dst], 1);
}

// single-block exclusive scan of deg[50000] -> rowptr[50001]; cursor = copy
__global__ __launch_bounds__(1024) void scan_kernel(const int* __restrict__ deg,
        int* __restrict__ rowptr, int* __restrict__ cursor) {
    __shared__ int part[1024];
    const int t = threadIdx.x;
    const int CHK = (N_NODES + 1023) / 1024;   // 49
    const int base = t * CHK;
    int s = 0;
    for (int i = 0; i < CHK; ++i) {
        int idx = base + i;
        if (idx < N_NODES) s += deg[idx];
    }
    part[t] = s;
    __syncthreads();
    for (int off = 1; off < 1024; off <<= 1) {
        int v = (t >= off) ? part[t - off] : 0;
        __syncthreads();
        part[t] += v;
        __syncthreads();
    }
    int run = (t == 0) ? 0 : part[t - 1];
    for (int i = 0; i < CHK; ++i) {
        int idx = base + i;
        if (idx < N_NODES) {
            rowptr[idx] = run;
            cursor[idx] = run;
            run += deg[idx];
        }
    }
    if (t == 0) rowptr[N_NODES] = E_TOT;
}

__global__ __launch_bounds__(256) void scatter_kernel(const int* __restrict__ ei,
        int* __restrict__ cursor, int* __restrict__ csr_src) {
    int j = blockIdx.x * 256 + threadIdx.x;
    if (j >= E_TOT) return;
    int src, dst;
    if (j < N_EDGES) { src = ei[j]; dst = ei[N_EDGES + j]; }
    else             { src = j - N_EDGES; dst = src; }
    int pos = atomicAdd(&cursor[dst], 1);
    csr_src[pos] = src;
}

// ================= softmax denominators (gather, no atomics)
// thread = (dst, head); writes ew in CSR order and sinv = 1/(8*sum)
__global__ __launch_bounds__(256) void denom_kernel(const int* __restrict__ rowptr,
        const int* __restrict__ csr_src, const float* __restrict__ asrc,
        const float* __restrict__ adst, float* __restrict__ ew,
        float* __restrict__ sinv) {
    int t = blockIdx.x * 256 + threadIdx.x;
    if (t >= N_NODES * NHEAD) return;
    int dst = t >> 3;
    int hd  = t & 7;
    float ad = adst[t];
    int p0 = rowptr[dst], p1 = rowptr[dst + 1];
    float sum = 0.f;
    for (int p = p0; p < p1; ++p) {
        int src = csr_src[p];
        float e = asrc[src * NHEAD + hd] + ad;
        e = e > 0.f ? e : NEG_SLOPE * e;
        float ex = __expf(e);
        ew[(size_t)p * NHEAD + hd] = ex;
        sum += ex;
    }
    sinv[t] = 1.0f / (8.0f * sum);
}

// ================= aggregation (gather, no atomics) + bias + ELU
// thread = (dst, channel)
__global__ __launch_bounds__(256) void aggregate_kernel(const int* __restrict__ rowptr,
        const int* __restrict__ csr_src, const float* __restrict__ ew,
        const float* __restrict__ sinv, const float* __restrict__ h,
        const float* __restrict__ b, float* __restrict__ out) {
    int t = blockIdx.x * 256 + threadIdx.x;
    if (t >= N_NODES * CH) return;
    int dst = t >> 5;
    int c   = t & 31;
    int p0 = rowptr[dst], p1 = rowptr[dst + 1];
    float acc[NHEAD];
    #pragma unroll
    for (int hd = 0; hd < NHEAD; ++hd) acc[hd] = 0.f;
    for (int p = p0; p < p1; ++p) {
        int src = csr_src[p];                       // broadcast across 32 lanes
        const float*  hp = h + (size_t)src * HC + c;
        const float4* wp = (const float4*)(ew + (size_t)p * NHEAD);
        float4 w0 = wp[0], w1 = wp[1];
        acc[0] += w0.x * hp[0 * CH];
        acc[1] += w0.y * hp[1 * CH];
        acc[2] += w0.z * hp[2 * CH];
        acc[3] += w0.w * hp[3 * CH];
        acc[4] += w1.x * hp[4 * CH];
        acc[5] += w1.y * hp[5 * CH];
        acc[6] += w1.z * hp[6 * CH];
        acc[7] += w1.w * hp[7 * CH];
    }
    const float* sp = sinv + (size_t)dst * NHEAD;
    float val = 0.f;
    #pragma unroll
    for (int hd = 0; hd < NHEAD; ++hd) val += sp[hd] * acc[hd];
    val += b[c];
    out[t] = val > 0.f ? val : (__expf(val) - 1.f);
}

// ================= output head: logits = h@Wo + bo, log_softmax (1 wave/node)
__global__ __launch_bounds__(64) void out_kernel(const float* __restrict__ hf,
        const float* __restrict__ Wo, const float* __restrict__ bo,
        float* __restrict__ out) {
    const int n = blockIdx.x;
    const int lane = threadIdx.x;
    __shared__ float hs[CH];
    if (lane < CH) hs[lane] = hf[n * CH + lane];
    __syncthreads();
    float logit = -INFINITY;
    if (lane < OUT_C) {
        float a = bo[lane];
        #pragma unroll
        for (int k = 0; k < CH; ++k) a += hs[k] * Wo[k * OUT_C + lane];
        logit = a;
    }
    float m = logit;
    #pragma unroll
    for (int off = 32; off; off >>= 1) m = fmaxf(m, __shfl_xor(m, off, 64));
    float ex = (lane < OUT_C) ? __expf(logit - m) : 0.f;
    float ssum = ex;
    #pragma unroll
    for (int off = 32; off; off >>= 1) ssum += __shfl_xor(ssum, off, 64);
    if (lane < OUT_C) out[(size_t)n * OUT_C + lane] = logit - m - __logf(ssum);
}

extern "C" void kernel_launch(void* const* d_in, const int* in_sizes, int n_in,
                              void* d_out, int out_size, void* d_ws, size_t ws_size,
                              hipStream_t stream) {
    const float* x      = (const float*)d_in[0];
    const int*   ei     = (const int*)  d_in[1];
    const float* W1     = (const float*)d_in[2];
    const float* a_src1 = (const float*)d_in[3];
    const float* a_dst1 = (const float*)d_in[4];
    const float* b1     = (const float*)d_in[5];
    const float* W2     = (const float*)d_in[6];
    const float* a_src2 = (const float*)d_in[7];
    const float* a_dst2 = (const float*)d_in[8];
    const float* b2     = (const float*)d_in[9];
    const float* Wo     = (const float*)d_in[10];
    const float* bo     = (const float*)d_in[11];
    float* out = (float*)d_out;

    // workspace carve-up (256B-aligned)
    char* ws = (char*)d_ws;
    size_t off = 0;
    auto carve = [&](size_t bytes) { char* p = ws + off; off += (bytes + 255) & ~(size_t)255; return p; };
    float* h_big   = (float*)carve((size_t)N_NODES * HC * 4);      // 51.2 MB
    float* asrc    = (float*)carve((size_t)N_NODES * NHEAD * 4);   // 1.6 MB
    float* adst    = (float*)carve((size_t)N_NODES * NHEAD * 4);
    float* sinv    = (float*)carve((size_t)N_NODES * NHEAD * 4);
    float* ew      = (float*)carve((size_t)E_TOT * NHEAD * 4);     // 27.2 MB
    float* hmid    = (float*)carve((size_t)N_NODES * CH * 4);      // 6.4 MB
    float* hout    = (float*)carve((size_t)N_NODES * CH * 4);      // 6.4 MB
    int*   deg     = (int*)  carve((size_t)N_NODES * 4);
    int*   rowptr  = (int*)  carve((size_t)(N_NODES + 1) * 4);
    int*   cursor  = (int*)  carve((size_t)N_NODES * 4);
    int*   csr_src = (int*)  carve((size_t)E_TOT * 4);             // 3.4 MB

    const int g_gemm1 = (N_NODES + G1_TR - 1) / G1_TR;       // 1563
    const int g_gemm2 = (N_NODES + G2_ROWS - 1) / G2_ROWS;   // 391
    const int g_nh    = (N_NODES * NHEAD + 255) / 256;       // 1563
    const int g_edge  = (E_TOT + 255) / 256;                 // 3321
    const int g_aggr  = (N_NODES * CH + 255) / 256;          // 6250

    // ---------- CSR build (shared by both layers) ----------
    hipMemsetAsync(deg, 0, (size_t)N_NODES * 4, stream);
    deg_kernel<<<g_edge, 256, 0, stream>>>(ei, deg);
    scan_kernel<<<1, 1024, 0, stream>>>(deg, rowptr, cursor);
    scatter_kernel<<<g_edge, 256, 0, stream>>>(ei, cursor, csr_src);

    // ---------- layer 1 ----------
    gemm1_kernel<<<g_gemm1, 256, 0, stream>>>(x, W1, h_big);
    alpha_kernel<<<g_nh, 256, 0, stream>>>(h_big, a_src1, a_dst1, asrc, adst);
    denom_kernel<<<g_nh, 256, 0, stream>>>(rowptr, csr_src, asrc, adst, ew, sinv);
    aggregate_kernel<<<g_aggr, 256, 0, stream>>>(rowptr, csr_src, ew, sinv, h_big, b1, hmid);

    // ---------- layer 2 ----------
    gemm2_kernel<<<g_gemm2, 256, 0, stream>>>(hmid, W2, h_big);
    alpha_kernel<<<g_nh, 256, 0, stream>>>(h_big, a_src2, a_dst2, asrc, adst);
    denom_kernel<<<g_nh, 256, 0, stream>>>(rowptr, csr_src, asrc, adst, ew, sinv);
    aggregate_kernel<<<g_aggr, 256, 0, stream>>>(rowptr, csr_src, ew, sinv, h_big, b2, hout);

    // ---------- output head ----------
    out_kernel<<<N_NODES, 64, 0, stream>>>(hout, Wo, bo, out);
}

// Round 7
// 807.854 us; speedup vs baseline: 2.4131x; 1.1559x over previous
//
#include <hip/hip_runtime.h>
#include <math.h>

#define N_NODES 50000
#define N_EDGES 800000
#define E_TOT   (N_EDGES + N_NODES)   // edges + self-loops = 850000
#define F_IN    256
#define NHEAD   8
#define CH      32
#define HC      256                   // NHEAD*CH
#define OUT_C   40
#define NEG_SLOPE 0.2f

// h is stored TRANSPOSED per node: ht[node*256 + c*8 + hd]  (c=channel, hd=head)
// so aggregate can read all 8 heads of one channel as two float4s.

// ================= GEMM1 + fused alpha: ht = x @ W1, asrc/adst = rowdot(a_src/a_dst)
// Block: 32 rows x 256 cols. Thread: 8 rows x 4 cols (acc[8] float4 = 32 VGPRs).
// Register history: r4 uncapped acc[16]x4 spilled (~320 demand); r5 cap-64 spilled;
// r6 natural alloc = 220 VGPR (full k4 unroll pipelines ~64 W loads) -> 2 waves/SIMD,
// VALUBusy 30%. Fix: unroll 2 -> ~110 VGPR -> 4-5 waves/SIMD.
#define G1_TR 32
#define G1_TK 64
__global__ __launch_bounds__(256) void gemm1_kernel(const float* __restrict__ x,
        const float* __restrict__ W, float* __restrict__ ht,
        const float* __restrict__ a_src, const float* __restrict__ a_dst,
        float* __restrict__ asrc, float* __restrict__ adst) {
    __shared__ float4 xs[G1_TR][G1_TK / 4];    // 32 x 16 float4 = 8 KB
    const int row0 = blockIdx.x * G1_TR;
    const int t    = threadIdx.x;
    const int lane = t & 63;       // cols lane*4 .. lane*4+3
    const int wrow = t >> 6;       // wave id 0..3 -> rows wrow*8 .. +7
    const int hd   = lane >> 3;          // head of this thread's 4 cols
    const int c0   = (lane & 7) * 4;     // channel base within head
    const float4* W4 = (const float4*)W;   // W4[k*64 + lane] = W[k][lane*4..+3]

    float4 acc[8];
    #pragma unroll
    for (int i = 0; i < 8; ++i) acc[i] = make_float4(0.f, 0.f, 0.f, 0.f);

    #pragma unroll 1
    for (int kt = 0; kt < F_IN; kt += G1_TK) {
        __syncthreads();
        for (int i = t; i < G1_TR * (G1_TK / 4); i += 256) {
            int r  = i >> 4;
            int k4 = i & 15;
            int gr = row0 + r;
            float4 v = make_float4(0.f, 0.f, 0.f, 0.f);
            if (gr < N_NODES) v = ((const float4*)(x + (size_t)gr * F_IN + kt))[k4];
            xs[r][k4] = v;
        }
        __syncthreads();
        #pragma unroll 2
        for (int k4 = 0; k4 < G1_TK / 4; ++k4) {
            int kbase = kt + k4 * 4;
            float4 w0 = W4[(kbase + 0) * 64 + lane];
            float4 w1 = W4[(kbase + 1) * 64 + lane];
            float4 w2 = W4[(kbase + 2) * 64 + lane];
            float4 w3 = W4[(kbase + 3) * 64 + lane];
            #pragma unroll
            for (int i = 0; i < 8; ++i) {
                float4 xv = xs[wrow * 8 + i][k4];   // wave-uniform -> LDS broadcast
                acc[i].x += xv.x * w0.x + xv.y * w1.x + xv.z * w2.x + xv.w * w3.x;
                acc[i].y += xv.x * w0.y + xv.y * w1.y + xv.z * w2.y + xv.w * w3.y;
                acc[i].z += xv.x * w0.z + xv.y * w1.z + xv.z * w2.z + xv.w * w3.z;
                acc[i].w += xv.x * w0.w + xv.y * w1.w + xv.z * w2.w + xv.w * w3.w;
            }
        }
    }

    const float4 as4 = *(const float4*)(a_src + hd * CH + c0);
    const float4 ad4 = *(const float4*)(a_dst + hd * CH + c0);
    #pragma unroll
    for (int i = 0; i < 8; ++i) {
        int gr = row0 + wrow * 8 + i;          // wave-uniform guard
        if (gr < N_NODES) {
            float* hr = ht + (size_t)gr * HC;
            hr[(c0 + 0) * 8 + hd] = acc[i].x;  // permutation within the 1KB row
            hr[(c0 + 1) * 8 + hd] = acc[i].y;
            hr[(c0 + 2) * 8 + hd] = acc[i].z;
            hr[(c0 + 3) * 8 + hd] = acc[i].w;
            float ps = acc[i].x * as4.x + acc[i].y * as4.y + acc[i].z * as4.z + acc[i].w * as4.w;
            float pd = acc[i].x * ad4.x + acc[i].y * ad4.y + acc[i].z * ad4.z + acc[i].w * ad4.w;
            ps += __shfl_xor(ps, 1, 64); ps += __shfl_xor(ps, 2, 64); ps += __shfl_xor(ps, 4, 64);
            pd += __shfl_xor(pd, 1, 64); pd += __shfl_xor(pd, 2, 64); pd += __shfl_xor(pd, 4, 64);
            if ((lane & 7) == 0) {
                asrc[gr * NHEAD + hd] = ps;
                adst[gr * NHEAD + hd] = pd;
            }
        }
    }
}

// ================= GEMM2 + fused alpha: ht = hm @ W2 (transposed store)
#define G2_ROWS 128
__global__ __launch_bounds__(256) void gemm2_kernel(const float* __restrict__ hm,
        const float* __restrict__ W, float* __restrict__ ht,
        const float* __restrict__ a_src, const float* __restrict__ a_dst,
        float* __restrict__ asrc, float* __restrict__ adst) {
    const int row0 = blockIdx.x * G2_ROWS;
    const int c  = threadIdx.x;
    const int hd = c >> 5;
    const int cc = c & 31;
    float w[CH];
    #pragma unroll
    for (int k = 0; k < CH; ++k) w[k] = W[k * HC + c];
    const float as = a_src[hd * CH + cc];
    const float ad = a_dst[hd * CH + cc];
    for (int i = 0; i < G2_ROWS; ++i) {
        int row = row0 + i;
        if (row >= N_NODES) break;                 // uniform
        const float* hr = hm + (size_t)row * CH;   // block-uniform -> scalar loads
        float a = 0.f;
        #pragma unroll
        for (int k = 0; k < CH; ++k) a += hr[k] * w[k];
        ht[(size_t)row * HC + cc * 8 + hd] = a;
        float ps = a * as, pd = a * ad;
        #pragma unroll
        for (int off = 1; off < 32; off <<= 1) {
            ps += __shfl_xor(ps, off, 64);
            pd += __shfl_xor(pd, off, 64);
        }
        if (cc == 0) {
            asrc[row * NHEAD + hd] = ps;
            adst[row * NHEAD + hd] = pd;
        }
    }
}

// ================= CSR build =================
__global__ __launch_bounds__(256) void deg_kernel(const int* __restrict__ ei,
        int* __restrict__ deg) {
    int j = blockIdx.x * 256 + threadIdx.x;
    if (j >= E_TOT) return;
    int dst = (j < N_EDGES) ? ei[N_EDGES + j] : (j - N_EDGES);
    atomicAdd(&deg[dst], 1);
}

__global__ __launch_bounds__(1024) void scan_kernel(const int* __restrict__ deg,
        int* __restrict__ rowptr, int* __restrict__ cursor) {
    __shared__ int part[1024];
    const int t = threadIdx.x;
    const int CHK = (N_NODES + 1023) / 1024;   // 49
    const int base = t * CHK;
    int s = 0;
    for (int i = 0; i < CHK; ++i) {
        int idx = base + i;
        if (idx < N_NODES) s += deg[idx];
    }
    part[t] = s;
    __syncthreads();
    for (int off = 1; off < 1024; off <<= 1) {
        int v = (t >= off) ? part[t - off] : 0;
        __syncthreads();
        part[t] += v;
        __syncthreads();
    }
    int run = (t == 0) ? 0 : part[t - 1];
    for (int i = 0; i < CHK; ++i) {
        int idx = base + i;
        if (idx < N_NODES) {
            rowptr[idx] = run;
            cursor[idx] = run;
            run += deg[idx];
        }
    }
    if (t == 0) rowptr[N_NODES] = E_TOT;
}

__global__ __launch_bounds__(256) void scatter_kernel(const int* __restrict__ ei,
        int* __restrict__ cursor, int* __restrict__ csr_src) {
    int j = blockIdx.x * 256 + threadIdx.x;
    if (j >= E_TOT) return;
    int src, dst;
    if (j < N_EDGES) { src = ei[j]; dst = ei[N_EDGES + j]; }
    else             { src = j - N_EDGES; dst = src; }
    int pos = atomicAdd(&cursor[dst], 1);
    csr_src[pos] = src;
}

// ================= softmax denominators (gather, no atomics)
__global__ __launch_bounds__(256) void denom_kernel(const int* __restrict__ rowptr,
        const int* __restrict__ csr_src, const float* __restrict__ asrc,
        const float* __restrict__ adst, float* __restrict__ ew,
        float* __restrict__ sinv) {
    int t = blockIdx.x * 256 + threadIdx.x;
    if (t >= N_NODES * NHEAD) return;
    int dst = t >> 3;
    int hd  = t & 7;
    float ad = adst[t];
    int p0 = rowptr[dst], p1 = rowptr[dst + 1];
    float sum = 0.f;
    for (int p = p0; p < p1; ++p) {
        int src = csr_src[p];
        float e = asrc[src * NHEAD + hd] + ad;
        e = e > 0.f ? e : NEG_SLOPE * e;
        float ex = __expf(e);
        ew[(size_t)p * NHEAD + hd] = ex;
        sum += ex;
    }
    sinv[t] = 1.0f / (8.0f * sum);
}

// ================= aggregation (gather, no atomics) + bias + ELU
// thread = (dst, channel); ht layout gives the 8 head-values as 2 float4s
__global__ __launch_bounds__(256) void aggregate_kernel(const int* __restrict__ rowptr,
        const int* __restrict__ csr_src, const float* __restrict__ ew,
        const float* __restrict__ sinv, const float* __restrict__ ht,
        const float* __restrict__ b, float* __restrict__ out) {
    int t = blockIdx.x * 256 + threadIdx.x;
    if (t >= N_NODES * CH) return;
    int dst = t >> 5;
    int c   = t & 31;
    int p0 = rowptr[dst], p1 = rowptr[dst + 1];
    float acc[NHEAD];
    #pragma unroll
    for (int hd = 0; hd < NHEAD; ++hd) acc[hd] = 0.f;
    for (int p = p0; p < p1; ++p) {
        int src = csr_src[p];                       // broadcast across 32 lanes
        const float4* hp = (const float4*)(ht + (size_t)src * HC + c * 8);
        const float4* wp = (const float4*)(ew + (size_t)p * NHEAD);
        float4 h0 = hp[0], h1 = hp[1];
        float4 w0 = wp[0], w1 = wp[1];
        acc[0] += w0.x * h0.x;
        acc[1] += w0.y * h0.y;
        acc[2] += w0.z * h0.z;
        acc[3] += w0.w * h0.w;
        acc[4] += w1.x * h1.x;
        acc[5] += w1.y * h1.y;
        acc[6] += w1.z * h1.z;
        acc[7] += w1.w * h1.w;
    }
    const float* sp = sinv + (size_t)dst * NHEAD;
    float val = 0.f;
    #pragma unroll
    for (int hd = 0; hd < NHEAD; ++hd) val += sp[hd] * acc[hd];
    val += b[c];
    out[t] = val > 0.f ? val : (__expf(val) - 1.f);
}

// ================= output head: logits = h@Wo + bo, log_softmax (1 wave/node)
__global__ __launch_bounds__(64) void out_kernel(const float* __restrict__ hf,
        const float* __restrict__ Wo, const float* __restrict__ bo,
        float* __restrict__ out) {
    const int n = blockIdx.x;
    const int lane = threadIdx.x;
    __shared__ float hs[CH];
    if (lane < CH) hs[lane] = hf[n * CH + lane];
    __syncthreads();
    float logit = -INFINITY;
    if (lane < OUT_C) {
        float a = bo[lane];
        #pragma unroll
        for (int k = 0; k < CH; ++k) a += hs[k] * Wo[k * OUT_C + lane];
        logit = a;
    }
    float m = logit;
    #pragma unroll
    for (int off = 32; off; off >>= 1) m = fmaxf(m, __shfl_xor(m, off, 64));
    float ex = (lane < OUT_C) ? __expf(logit - m) : 0.f;
    float ssum = ex;
    #pragma unroll
    for (int off = 32; off; off >>= 1) ssum += __shfl_xor(ssum, off, 64);
    if (lane < OUT_C) out[(size_t)n * OUT_C + lane] = logit - m - __logf(ssum);
}

extern "C" void kernel_launch(void* const* d_in, const int* in_sizes, int n_in,
                              void* d_out, int out_size, void* d_ws, size_t ws_size,
                              hipStream_t stream) {
    const float* x      = (const float*)d_in[0];
    const int*   ei     = (const int*)  d_in[1];
    const float* W1     = (const float*)d_in[2];
    const float* a_src1 = (const float*)d_in[3];
    const float* a_dst1 = (const float*)d_in[4];
    const float* b1     = (const float*)d_in[5];
    const float* W2     = (const float*)d_in[6];
    const float* a_src2 = (const float*)d_in[7];
    const float* a_dst2 = (const float*)d_in[8];
    const float* b2     = (const float*)d_in[9];
    const float* Wo     = (const float*)d_in[10];
    const float* bo     = (const float*)d_in[11];
    float* out = (float*)d_out;

    // workspace carve-up (256B-aligned)
    char* ws = (char*)d_ws;
    size_t off = 0;
    auto carve = [&](size_t bytes) { char* p = ws + off; off += (bytes + 255) & ~(size_t)255; return p; };
    float* h_big   = (float*)carve((size_t)N_NODES * HC * 4);      // 51.2 MB (transposed h)
    float* asrc    = (float*)carve((size_t)N_NODES * NHEAD * 4);   // 1.6 MB
    float* adst    = (float*)carve((size_t)N_NODES * NHEAD * 4);
    float* sinv    = (float*)carve((size_t)N_NODES * NHEAD * 4);
    float* ew      = (float*)carve((size_t)E_TOT * NHEAD * 4);     // 27.2 MB
    float* hmid    = (float*)carve((size_t)N_NODES * CH * 4);      // 6.4 MB
    float* hout    = (float*)carve((size_t)N_NODES * CH * 4);      // 6.4 MB
    int*   deg     = (int*)  carve((size_t)N_NODES * 4);
    int*   rowptr  = (int*)  carve((size_t)(N_NODES + 1) * 4);
    int*   cursor  = (int*)  carve((size_t)N_NODES * 4);
    int*   csr_src = (int*)  carve((size_t)E_TOT * 4);             // 3.4 MB

    const int g_gemm1 = (N_NODES + G1_TR - 1) / G1_TR;       // 1563
    const int g_gemm2 = (N_NODES + G2_ROWS - 1) / G2_ROWS;   // 391
    const int g_nh    = (N_NODES * NHEAD + 255) / 256;       // 1563
    const int g_edge  = (E_TOT + 255) / 256;                 // 3321
    const int g_aggr  = (N_NODES * CH + 255) / 256;          // 6250

    // ---------- CSR build (shared by both layers) ----------
    hipMemsetAsync(deg, 0, (size_t)N_NODES * 4, stream);
    deg_kernel<<<g_edge, 256, 0, stream>>>(ei, deg);
    scan_kernel<<<1, 1024, 0, stream>>>(deg, rowptr, cursor);
    scatter_kernel<<<g_edge, 256, 0, stream>>>(ei, cursor, csr_src);

    // ---------- layer 1 ----------
    gemm1_kernel<<<g_gemm1, 256, 0, stream>>>(x, W1, h_big, a_src1, a_dst1, asrc, adst);
    denom_kernel<<<g_nh, 256, 0, stream>>>(rowptr, csr_src, asrc, adst, ew, sinv);
    aggregate_kernel<<<g_aggr, 256, 0, stream>>>(rowptr, csr_src, ew, sinv, h_big, b1, hmid);

    // ---------- layer 2 ----------
    gemm2_kernel<<<g_gemm2, 256, 0, stream>>>(hmid, W2, h_big, a_src2, a_dst2, asrc, adst);
    denom_kernel<<<g_nh, 256, 0, stream>>>(rowptr, csr_src, asrc, adst, ew, sinv);
    aggregate_kernel<<<g_aggr, 256, 0, stream>>>(rowptr, csr_src, ew, sinv, h_big, b2, hout);

    // ---------- output head ----------
    out_kernel<<<N_NODES, 64, 0, stream>>>(hout, Wo, bo, out);
}

// Round 8
// 696.468 us; speedup vs baseline: 2.7991x; 1.1599x over previous
//
#include <hip/hip_runtime.h>
#include <math.h>

#define N_NODES 50000
#define N_EDGES 800000
#define E_TOT   (N_EDGES + N_NODES)   // edges + self-loops = 850000
#define F_IN    256
#define NHEAD   8
#define CH      32
#define HC      256                   // NHEAD*CH
#define OUT_C   40
#define NEG_SLOPE 0.2f

typedef unsigned short u16;
typedef unsigned int   u32;

__device__ __forceinline__ u16 f2bf(float f) {
    union { u32 u; float f; } x; x.f = f;
    u32 u = x.u;
    return (u16)((u + 0x7fffu + ((u >> 16) & 1u)) >> 16);   // round-nearest-even
}
__device__ __forceinline__ float bflo(u32 v) {
    union { u32 u; float f; } x; x.u = v << 16; return x.f;
}
__device__ __forceinline__ float bfhi(u32 v) {
    union { u32 u; float f; } x; x.u = v & 0xffff0000u; return x.f;
}

// ht is bf16, TRANSPOSED per node: ht[node*256 + c*8 + hd] -> the 8 head-values
// of channel c are 16 contiguous bytes (one uint4 gather in attn_kernel).

// ================= GEMM1 + fused alpha: ht = bf16(x @ W1), asrc/adst = rowdot
// Block: 32 rows x 256 cols. Thread: 8 rows x 4 cols (acc[8] float4).
// Register history: r4 uncapped acc[16]x4 -> spill; r5 cap-64 -> spill;
// r6 full unroll -> 220 VGPR, 2 waves/SIMD; r7 unroll 2 -> 64 VGPR, 133us. Keep.
#define G1_TR 32
#define G1_TK 64
__global__ __launch_bounds__(256) void gemm1_kernel(const float* __restrict__ x,
        const float* __restrict__ W, u16* __restrict__ ht,
        const float* __restrict__ a_src, const float* __restrict__ a_dst,
        float* __restrict__ asrc, float* __restrict__ adst) {
    __shared__ float4 xs[G1_TR][G1_TK / 4];    // 8 KB
    const int row0 = blockIdx.x * G1_TR;
    const int t    = threadIdx.x;
    const int lane = t & 63;       // cols lane*4 .. lane*4+3
    const int wrow = t >> 6;       // wave id 0..3 -> rows wrow*8 .. +7
    const int hd   = lane >> 3;          // head of this thread's 4 cols
    const int c0   = (lane & 7) * 4;     // channel base within head
    const float4* W4 = (const float4*)W;

    float4 acc[8];
    #pragma unroll
    for (int i = 0; i < 8; ++i) acc[i] = make_float4(0.f, 0.f, 0.f, 0.f);

    #pragma unroll 1
    for (int kt = 0; kt < F_IN; kt += G1_TK) {
        __syncthreads();
        for (int i = t; i < G1_TR * (G1_TK / 4); i += 256) {
            int r  = i >> 4;
            int k4 = i & 15;
            int gr = row0 + r;
            float4 v = make_float4(0.f, 0.f, 0.f, 0.f);
            if (gr < N_NODES) v = ((const float4*)(x + (size_t)gr * F_IN + kt))[k4];
            xs[r][k4] = v;
        }
        __syncthreads();
        #pragma unroll 2
        for (int k4 = 0; k4 < G1_TK / 4; ++k4) {
            int kbase = kt + k4 * 4;
            float4 w0 = W4[(kbase + 0) * 64 + lane];
            float4 w1 = W4[(kbase + 1) * 64 + lane];
            float4 w2 = W4[(kbase + 2) * 64 + lane];
            float4 w3 = W4[(kbase + 3) * 64 + lane];
            #pragma unroll
            for (int i = 0; i < 8; ++i) {
                float4 xv = xs[wrow * 8 + i][k4];   // wave-uniform -> LDS broadcast
                acc[i].x += xv.x * w0.x + xv.y * w1.x + xv.z * w2.x + xv.w * w3.x;
                acc[i].y += xv.x * w0.y + xv.y * w1.y + xv.z * w2.y + xv.w * w3.y;
                acc[i].z += xv.x * w0.z + xv.y * w1.z + xv.z * w2.z + xv.w * w3.z;
                acc[i].w += xv.x * w0.w + xv.y * w1.w + xv.z * w2.w + xv.w * w3.w;
            }
        }
    }

    const float4 as4 = *(const float4*)(a_src + hd * CH + c0);
    const float4 ad4 = *(const float4*)(a_dst + hd * CH + c0);
    #pragma unroll
    for (int i = 0; i < 8; ++i) {
        int gr = row0 + wrow * 8 + i;          // wave-uniform guard
        if (gr < N_NODES) {
            u16* hr = ht + (size_t)gr * HC;
            hr[(c0 + 0) * 8 + hd] = f2bf(acc[i].x);
            hr[(c0 + 1) * 8 + hd] = f2bf(acc[i].y);
            hr[(c0 + 2) * 8 + hd] = f2bf(acc[i].z);
            hr[(c0 + 3) * 8 + hd] = f2bf(acc[i].w);
            float ps = acc[i].x * as4.x + acc[i].y * as4.y + acc[i].z * as4.z + acc[i].w * as4.w;
            float pd = acc[i].x * ad4.x + acc[i].y * ad4.y + acc[i].z * ad4.z + acc[i].w * ad4.w;
            ps += __shfl_xor(ps, 1, 64); ps += __shfl_xor(ps, 2, 64); ps += __shfl_xor(ps, 4, 64);
            pd += __shfl_xor(pd, 1, 64); pd += __shfl_xor(pd, 2, 64); pd += __shfl_xor(pd, 4, 64);
            if ((lane & 7) == 0) {
                asrc[gr * NHEAD + hd] = ps;
                adst[gr * NHEAD + hd] = pd;
            }
        }
    }
}

// ================= GEMM2 + fused alpha: ht = bf16(hm @ W2) (transposed store)
#define G2_ROWS 128
__global__ __launch_bounds__(256) void gemm2_kernel(const float* __restrict__ hm,
        const float* __restrict__ W, u16* __restrict__ ht,
        const float* __restrict__ a_src, const float* __restrict__ a_dst,
        float* __restrict__ asrc, float* __restrict__ adst) {
    const int row0 = blockIdx.x * G2_ROWS;
    const int c  = threadIdx.x;
    const int hd = c >> 5;
    const int cc = c & 31;
    float w[CH];
    #pragma unroll
    for (int k = 0; k < CH; ++k) w[k] = W[k * HC + c];
    const float as = a_src[hd * CH + cc];
    const float ad = a_dst[hd * CH + cc];
    for (int i = 0; i < G2_ROWS; ++i) {
        int row = row0 + i;
        if (row >= N_NODES) break;                 // uniform
        const float* hr = hm + (size_t)row * CH;   // block-uniform -> scalar loads
        float a = 0.f;
        #pragma unroll
        for (int k = 0; k < CH; ++k) a += hr[k] * w[k];
        ht[(size_t)row * HC + cc * 8 + hd] = f2bf(a);
        float ps = a * as, pd = a * ad;
        #pragma unroll
        for (int off = 1; off < 32; off <<= 1) {
            ps += __shfl_xor(ps, off, 64);
            pd += __shfl_xor(pd, off, 64);
        }
        if (cc == 0) {
            asrc[row * NHEAD + hd] = ps;
            adst[row * NHEAD + hd] = pd;
        }
    }
}

// ================= CSR build =================
__global__ __launch_bounds__(256) void deg_kernel(const int* __restrict__ ei,
        int* __restrict__ deg) {
    int j = blockIdx.x * 256 + threadIdx.x;
    if (j >= E_TOT) return;
    int dst = (j < N_EDGES) ? ei[N_EDGES + j] : (j - N_EDGES);
    atomicAdd(&deg[dst], 1);
}

__global__ __launch_bounds__(1024) void scan_kernel(const int* __restrict__ deg,
        int* __restrict__ rowptr, int* __restrict__ cursor) {
    __shared__ int part[1024];
    const int t = threadIdx.x;
    const int CHK = (N_NODES + 1023) / 1024;   // 49
    const int base = t * CHK;
    int s = 0;
    for (int i = 0; i < CHK; ++i) {
        int idx = base + i;
        if (idx < N_NODES) s += deg[idx];
    }
    part[t] = s;
    __syncthreads();
    for (int off = 1; off < 1024; off <<= 1) {
        int v = (t >= off) ? part[t - off] : 0;
        __syncthreads();
        part[t] += v;
        __syncthreads();
    }
    int run = (t == 0) ? 0 : part[t - 1];
    for (int i = 0; i < CHK; ++i) {
        int idx = base + i;
        if (idx < N_NODES) {
            rowptr[idx] = run;
            cursor[idx] = run;
            run += deg[idx];
        }
    }
    if (t == 0) rowptr[N_NODES] = E_TOT;
}

__global__ __launch_bounds__(256) void scatter_kernel(const int* __restrict__ ei,
        int* __restrict__ cursor, int* __restrict__ csr_src) {
    int j = blockIdx.x * 256 + threadIdx.x;
    if (j >= E_TOT) return;
    int src, dst;
    if (j < N_EDGES) { src = ei[j]; dst = ei[N_EDGES + j]; }
    else             { src = j - N_EDGES; dst = src; }
    int pos = atomicAdd(&cursor[dst], 1);
    csr_src[pos] = src;
}

// ================= fused attention: softmax + aggregate in ONE pass
// out[dst][c] = ELU( b[c] + sum_hd acc[hd] / (8 * wsum[hd]) )
// Normalization commutes with aggregation -> no ew array, no second edge pass.
// thread = (dst, channel); the 8 exps/lane are redundant x32 but cheap (~11us).
__global__ __launch_bounds__(256) void attn_kernel(const int* __restrict__ rowptr,
        const int* __restrict__ csr_src, const float* __restrict__ asrc,
        const float* __restrict__ adst, const u16* __restrict__ ht,
        const float* __restrict__ b, float* __restrict__ out) {
    int t = blockIdx.x * 256 + threadIdx.x;
    if (t >= N_NODES * CH) return;
    int dst = t >> 5;
    int c   = t & 31;
    const float4* A4 = (const float4*)asrc;
    const float4 ad0 = ((const float4*)adst)[dst * 2 + 0];   // broadcast
    const float4 ad1 = ((const float4*)adst)[dst * 2 + 1];
    const uint4* H4 = (const uint4*)ht;   // row = 32 uint4; lane c reads uint4 #c

    float acc[NHEAD], wsum[NHEAD];
    #pragma unroll
    for (int h = 0; h < NHEAD; ++h) { acc[h] = 0.f; wsum[h] = 0.f; }

    int p0 = rowptr[dst], p1 = rowptr[dst + 1];
    for (int p = p0; p < p1; ++p) {
        int src = csr_src[p];                       // broadcast across 32 lanes
        float4 s0 = A4[src * 2 + 0];                // broadcast 32B
        float4 s1 = A4[src * 2 + 1];
        float e0 = s0.x + ad0.x, e1 = s0.y + ad0.y, e2 = s0.z + ad0.z, e3 = s0.w + ad0.w;
        float e4 = s1.x + ad1.x, e5 = s1.y + ad1.y, e6 = s1.z + ad1.z, e7 = s1.w + ad1.w;
        e0 = e0 > 0.f ? e0 : NEG_SLOPE * e0;  e1 = e1 > 0.f ? e1 : NEG_SLOPE * e1;
        e2 = e2 > 0.f ? e2 : NEG_SLOPE * e2;  e3 = e3 > 0.f ? e3 : NEG_SLOPE * e3;
        e4 = e4 > 0.f ? e4 : NEG_SLOPE * e4;  e5 = e5 > 0.f ? e5 : NEG_SLOPE * e5;
        e6 = e6 > 0.f ? e6 : NEG_SLOPE * e6;  e7 = e7 > 0.f ? e7 : NEG_SLOPE * e7;
        float w0 = __expf(e0), w1 = __expf(e1), w2 = __expf(e2), w3 = __expf(e3);
        float w4 = __expf(e4), w5 = __expf(e5), w6 = __expf(e6), w7 = __expf(e7);
        wsum[0] += w0; wsum[1] += w1; wsum[2] += w2; wsum[3] += w3;
        wsum[4] += w4; wsum[5] += w5; wsum[6] += w6; wsum[7] += w7;
        uint4 hv = H4[(size_t)src * 32 + c];        // 16B gather: 8 bf16 head-vals
        acc[0] += w0 * bflo(hv.x);  acc[1] += w1 * bfhi(hv.x);
        acc[2] += w2 * bflo(hv.y);  acc[3] += w3 * bfhi(hv.y);
        acc[4] += w4 * bflo(hv.z);  acc[5] += w5 * bfhi(hv.z);
        acc[6] += w6 * bflo(hv.w);  acc[7] += w7 * bfhi(hv.w);
    }
    float val = 0.f;
    #pragma unroll
    for (int h = 0; h < NHEAD; ++h) val += acc[h] / wsum[h];
    val = val * 0.125f + b[c];
    out[t] = val > 0.f ? val : (__expf(val) - 1.f);
}

// ================= output head: logits = h@Wo + bo, log_softmax (1 wave/node)
__global__ __launch_bounds__(64) void out_kernel(const float* __restrict__ hf,
        const float* __restrict__ Wo, const float* __restrict__ bo,
        float* __restrict__ out) {
    const int n = blockIdx.x;
    const int lane = threadIdx.x;
    __shared__ float hs[CH];
    if (lane < CH) hs[lane] = hf[n * CH + lane];
    __syncthreads();
    float logit = -INFINITY;
    if (lane < OUT_C) {
        float a = bo[lane];
        #pragma unroll
        for (int k = 0; k < CH; ++k) a += hs[k] * Wo[k * OUT_C + lane];
        logit = a;
    }
    float m = logit;
    #pragma unroll
    for (int off = 32; off; off >>= 1) m = fmaxf(m, __shfl_xor(m, off, 64));
    float ex = (lane < OUT_C) ? __expf(logit - m) : 0.f;
    float ssum = ex;
    #pragma unroll
    for (int off = 32; off; off >>= 1) ssum += __shfl_xor(ssum, off, 64);
    if (lane < OUT_C) out[(size_t)n * OUT_C + lane] = logit - m - __logf(ssum);
}

extern "C" void kernel_launch(void* const* d_in, const int* in_sizes, int n_in,
                              void* d_out, int out_size, void* d_ws, size_t ws_size,
                              hipStream_t stream) {
    const float* x      = (const float*)d_in[0];
    const int*   ei     = (const int*)  d_in[1];
    const float* W1     = (const float*)d_in[2];
    const float* a_src1 = (const float*)d_in[3];
    const float* a_dst1 = (const float*)d_in[4];
    const float* b1     = (const float*)d_in[5];
    const float* W2     = (const float*)d_in[6];
    const float* a_src2 = (const float*)d_in[7];
    const float* a_dst2 = (const float*)d_in[8];
    const float* b2     = (const float*)d_in[9];
    const float* Wo     = (const float*)d_in[10];
    const float* bo     = (const float*)d_in[11];
    float* out = (float*)d_out;

    // workspace carve-up (256B-aligned)
    char* ws = (char*)d_ws;
    size_t off = 0;
    auto carve = [&](size_t bytes) { char* p = ws + off; off += (bytes + 255) & ~(size_t)255; return p; };
    u16*   ht      = (u16*)  carve((size_t)N_NODES * HC * 2);      // 25.6 MB (bf16, transposed)
    float* asrc    = (float*)carve((size_t)N_NODES * NHEAD * 4);   // 1.6 MB
    float* adst    = (float*)carve((size_t)N_NODES * NHEAD * 4);
    float* hmid    = (float*)carve((size_t)N_NODES * CH * 4);      // 6.4 MB
    float* hout    = (float*)carve((size_t)N_NODES * CH * 4);      // 6.4 MB
    int*   deg     = (int*)  carve((size_t)N_NODES * 4);
    int*   rowptr  = (int*)  carve((size_t)(N_NODES + 1) * 4);
    int*   cursor  = (int*)  carve((size_t)N_NODES * 4);
    int*   csr_src = (int*)  carve((size_t)E_TOT * 4);             // 3.4 MB

    const int g_gemm1 = (N_NODES + G1_TR - 1) / G1_TR;       // 1563
    const int g_gemm2 = (N_NODES + G2_ROWS - 1) / G2_ROWS;   // 391
    const int g_edge  = (E_TOT + 255) / 256;                 // 3321
    const int g_attn  = (N_NODES * CH + 255) / 256;          // 6250

    // ---------- CSR build (shared by both layers) ----------
    hipMemsetAsync(deg, 0, (size_t)N_NODES * 4, stream);
    deg_kernel<<<g_edge, 256, 0, stream>>>(ei, deg);
    scan_kernel<<<1, 1024, 0, stream>>>(deg, rowptr, cursor);
    scatter_kernel<<<g_edge, 256, 0, stream>>>(ei, cursor, csr_src);

    // ---------- layer 1 ----------
    gemm1_kernel<<<g_gemm1, 256, 0, stream>>>(x, W1, ht, a_src1, a_dst1, asrc, adst);
    attn_kernel<<<g_attn, 256, 0, stream>>>(rowptr, csr_src, asrc, adst, ht, b1, hmid);

    // ---------- layer 2 ----------
    gemm2_kernel<<<g_gemm2, 256, 0, stream>>>(hmid, W2, ht, a_src2, a_dst2, asrc, adst);
    attn_kernel<<<g_attn, 256, 0, stream>>>(rowptr, csr_src, asrc, adst, ht, b2, hout);

    // ---------- output head ----------
    out_kernel<<<N_NODES, 64, 0, stream>>>(hout, Wo, bo, out);
}

// Round 9
// 661.618 us; speedup vs baseline: 2.9465x; 1.0527x over previous
//
#include <hip/hip_runtime.h>
#include <math.h>

#define N_NODES 50000
#define N_PAD   50016                 // padded to 32-row gemm tiles
#define N_EDGES 800000
#define E_TOT   (N_EDGES + N_NODES)   // edges + self-loops = 850000
#define F_IN    256
#define NHEAD   8
#define CH      32
#define HC      256                   // NHEAD*CH
#define OUT_C   40
#define NEG_SLOPE 0.2f

typedef unsigned short u16;
typedef unsigned int   u32;
typedef __attribute__((ext_vector_type(8))) short bf16x8;   // 4 VGPRs
typedef __attribute__((ext_vector_type(4))) float f32x4;

__device__ __forceinline__ u16 f2bf(float f) {
    union { u32 u; float f; } x; x.f = f;
    u32 u = x.u;
    return (u16)((u + 0x7fffu + ((u >> 16) & 1u)) >> 16);   // round-nearest-even
}
__device__ __forceinline__ float bflo(u32 v) {
    union { u32 u; float f; } x; x.u = v << 16; return x.f;
}
__device__ __forceinline__ float bfhi(u32 v) {
    union { u32 u; float f; } x; x.u = v & 0xffff0000u; return x.f;
}

// ht is bf16, TRANSPOSED per node: ht[node*256 + c*8 + hd] -> the 8 head-values
// of channel c are 16 contiguous bytes (one uint4 gather in attn_kernel).

// ================= prep: x -> bf16 (row layout unchanged)
__global__ __launch_bounds__(256) void xcvt_kernel(const float* __restrict__ x,
        u16* __restrict__ xb) {
    int t = blockIdx.x * 256 + threadIdx.x;          // one per 8 elements
    if (t >= N_NODES * F_IN / 8) return;
    const float4* xp = (const float4*)x + (size_t)t * 2;
    float4 v0 = xp[0], v1 = xp[1];
    uint4 o;
    o.x = (u32)f2bf(v0.x) | ((u32)f2bf(v0.y) << 16);
    o.y = (u32)f2bf(v0.z) | ((u32)f2bf(v0.w) << 16);
    o.z = (u32)f2bf(v1.x) | ((u32)f2bf(v1.y) << 16);
    o.w = (u32)f2bf(v1.z) | ((u32)f2bf(v1.w) << 16);
    ((uint4*)xb)[t] = o;
}

// ================= prep: Wt[n][k] = bf16(W1[k][n])  (transpose for B-frags)
__global__ __launch_bounds__(256) void wcvt_kernel(const float* __restrict__ W,
        u16* __restrict__ Wt) {
    int t = blockIdx.x * 256 + threadIdx.x;          // 65536 total
    int n = t & 255, k = t >> 8;                     // coalesced reads
    Wt[(size_t)n * F_IN + k] = f2bf(W[(size_t)k * HC + n]);
}

// ================= GEMM1 via MFMA bf16: ht = bf16(x @ W1), transposed store
// Block: 32 rows x 256 cols, 4 waves; wave w -> cols w*64..+63.
// Wave: 2 M-tiles x 4 N-tiles of 16x16, K=256 in 8 steps of 32.
// Frags (verified layouts): A[m=lane&15][k=quad*8+j]; B from Wt[n][k] (n=lane&15);
// C/D: col=lane&15, row=quad*4+reg. No LDS; frag loads are 16B global (L1/L2).
__global__ __launch_bounds__(256) void gemm1_mfma(const u16* __restrict__ xb,
        const u16* __restrict__ Wt, u16* __restrict__ ht) {
    const int row0 = blockIdx.x * 32;
    const int t    = threadIdx.x;
    const int wave = t >> 6;
    const int lane = t & 63;
    const int l16  = lane & 15;
    const int quad = lane >> 4;
    const int nb   = wave * 64;

    f32x4 acc[2][4];
    #pragma unroll
    for (int m = 0; m < 2; ++m)
        #pragma unroll
        for (int n = 0; n < 4; ++n) acc[m][n] = (f32x4){0.f, 0.f, 0.f, 0.f};

    const u16* a0p = xb + (size_t)(row0 + l16) * F_IN;        // M-tile 0
    const u16* a1p = a0p + 16 * F_IN;                         // M-tile 1
    const u16* bp  = Wt + (size_t)(nb + l16) * F_IN;          // N-tile stride 16*F_IN

    #pragma unroll 1
    for (int k0 = 0; k0 < F_IN; k0 += 32) {
        const int ko = k0 + quad * 8;
        bf16x8 a0 = *(const bf16x8*)(a0p + ko);
        bf16x8 a1 = *(const bf16x8*)(a1p + ko);
        bf16x8 b0 = *(const bf16x8*)(bp + 0 * 16 * F_IN + ko);
        bf16x8 b1 = *(const bf16x8*)(bp + 1 * 16 * F_IN + ko);
        bf16x8 b2 = *(const bf16x8*)(bp + 2 * 16 * F_IN + ko);
        bf16x8 b3 = *(const bf16x8*)(bp + 3 * 16 * F_IN + ko);
        acc[0][0] = __builtin_amdgcn_mfma_f32_16x16x32_bf16(a0, b0, acc[0][0], 0, 0, 0);
        acc[0][1] = __builtin_amdgcn_mfma_f32_16x16x32_bf16(a0, b1, acc[0][1], 0, 0, 0);
        acc[0][2] = __builtin_amdgcn_mfma_f32_16x16x32_bf16(a0, b2, acc[0][2], 0, 0, 0);
        acc[0][3] = __builtin_amdgcn_mfma_f32_16x16x32_bf16(a0, b3, acc[0][3], 0, 0, 0);
        acc[1][0] = __builtin_amdgcn_mfma_f32_16x16x32_bf16(a1, b0, acc[1][0], 0, 0, 0);
        acc[1][1] = __builtin_amdgcn_mfma_f32_16x16x32_bf16(a1, b1, acc[1][1], 0, 0, 0);
        acc[1][2] = __builtin_amdgcn_mfma_f32_16x16x32_bf16(a1, b2, acc[1][2], 0, 0, 0);
        acc[1][3] = __builtin_amdgcn_mfma_f32_16x16x32_bf16(a1, b3, acc[1][3], 0, 0, 0);
    }

    #pragma unroll
    for (int m = 0; m < 2; ++m) {
        #pragma unroll
        for (int r = 0; r < 4; ++r) {
            int row = row0 + m * 16 + quad * 4 + r;
            if (row < N_NODES) {
                u16* hr = ht + (size_t)row * HC;
                #pragma unroll
                for (int n = 0; n < 4; ++n) {
                    int col = nb + n * 16 + l16;
                    int hd = col >> 5, cc = col & 31;
                    hr[cc * 8 + hd] = f2bf(acc[m][n][r]);
                }
            }
        }
    }
}

// ================= alpha from transposed bf16 ht: asrc/adst [N,8]
__global__ __launch_bounds__(256) void alpha_t_kernel(const u16* __restrict__ ht,
        const float* __restrict__ a_src, const float* __restrict__ a_dst,
        float* __restrict__ asrc, float* __restrict__ adst) {
    int t = blockIdx.x * 256 + threadIdx.x;
    if (t >= N_NODES * NHEAD) return;
    int node = t >> 3;
    int hd   = t & 7;
    const u16* hp = ht + (size_t)node * HC + hd;
    const float* ap = a_src + hd * CH;
    const float* dp = a_dst + hd * CH;
    float s1 = 0.f, s2 = 0.f;
    #pragma unroll
    for (int c = 0; c < CH; ++c) {
        float hv = bflo((u32)hp[c * 8]);
        s1 += hv * ap[c];
        s2 += hv * dp[c];
    }
    asrc[t] = s1;
    adst[t] = s2;
}

// ================= GEMM2 + fused alpha: ht = bf16(hm @ W2) (transposed store)
#define G2_ROWS 128
__global__ __launch_bounds__(256) void gemm2_kernel(const float* __restrict__ hm,
        const float* __restrict__ W, u16* __restrict__ ht,
        const float* __restrict__ a_src, const float* __restrict__ a_dst,
        float* __restrict__ asrc, float* __restrict__ adst) {
    const int row0 = blockIdx.x * G2_ROWS;
    const int c  = threadIdx.x;
    const int hd = c >> 5;
    const int cc = c & 31;
    float w[CH];
    #pragma unroll
    for (int k = 0; k < CH; ++k) w[k] = W[k * HC + c];
    const float as = a_src[hd * CH + cc];
    const float ad = a_dst[hd * CH + cc];
    for (int i = 0; i < G2_ROWS; ++i) {
        int row = row0 + i;
        if (row >= N_NODES) break;                 // uniform
        const float* hr = hm + (size_t)row * CH;   // block-uniform -> scalar loads
        float a = 0.f;
        #pragma unroll
        for (int k = 0; k < CH; ++k) a += hr[k] * w[k];
        ht[(size_t)row * HC + cc * 8 + hd] = f2bf(a);
        float ps = a * as, pd = a * ad;
        #pragma unroll
        for (int off = 1; off < 32; off <<= 1) {
            ps += __shfl_xor(ps, off, 64);
            pd += __shfl_xor(pd, off, 64);
        }
        if (cc == 0) {
            asrc[row * NHEAD + hd] = ps;
            adst[row * NHEAD + hd] = pd;
        }
    }
}

// ================= CSR build =================
__global__ __launch_bounds__(256) void deg_kernel(const int* __restrict__ ei,
        int* __restrict__ deg) {
    int j = blockIdx.x * 256 + threadIdx.x;
    if (j >= E_TOT) return;
    int dst = (j < N_EDGES) ? ei[N_EDGES + j] : (j - N_EDGES);
    atomicAdd(&deg[dst], 1);
}

__global__ __launch_bounds__(1024) void scan_kernel(const int* __restrict__ deg,
        int* __restrict__ rowptr, int* __restrict__ cursor) {
    __shared__ int part[1024];
    const int t = threadIdx.x;
    const int CHK = (N_NODES + 1023) / 1024;   // 49
    const int base = t * CHK;
    int s = 0;
    for (int i = 0; i < CHK; ++i) {
        int idx = base + i;
        if (idx < N_NODES) s += deg[idx];
    }
    part[t] = s;
    __syncthreads();
    for (int off = 1; off < 1024; off <<= 1) {
        int v = (t >= off) ? part[t - off] : 0;
        __syncthreads();
        part[t] += v;
        __syncthreads();
    }
    int run = (t == 0) ? 0 : part[t - 1];
    for (int i = 0; i < CHK; ++i) {
        int idx = base + i;
        if (idx < N_NODES) {
            rowptr[idx] = run;
            cursor[idx] = run;
            run += deg[idx];
        }
    }
    if (t == 0) rowptr[N_NODES] = E_TOT;
}

__global__ __launch_bounds__(256) void scatter_kernel(const int* __restrict__ ei,
        int* __restrict__ cursor, int* __restrict__ csr_src) {
    int j = blockIdx.x * 256 + threadIdx.x;
    if (j >= E_TOT) return;
    int src, dst;
    if (j < N_EDGES) { src = ei[j]; dst = ei[N_EDGES + j]; }
    else             { src = j - N_EDGES; dst = src; }
    int pos = atomicAdd(&cursor[dst], 1);
    csr_src[pos] = src;
}

// ================= fused attention: softmax + aggregate in ONE pass
__global__ __launch_bounds__(256) void attn_kernel(const int* __restrict__ rowptr,
        const int* __restrict__ csr_src, const float* __restrict__ asrc,
        const float* __restrict__ adst, const u16* __restrict__ ht,
        const float* __restrict__ b, float* __restrict__ out) {
    int t = blockIdx.x * 256 + threadIdx.x;
    if (t >= N_NODES * CH) return;
    int dst = t >> 5;
    int c   = t & 31;
    const float4* A4 = (const float4*)asrc;
    const float4 ad0 = ((const float4*)adst)[dst * 2 + 0];   // broadcast
    const float4 ad1 = ((const float4*)adst)[dst * 2 + 1];
    const uint4* H4 = (const uint4*)ht;   // row = 32 uint4; lane c reads uint4 #c

    float acc[NHEAD], wsum[NHEAD];
    #pragma unroll
    for (int h = 0; h < NHEAD; ++h) { acc[h] = 0.f; wsum[h] = 0.f; }

    int p0 = rowptr[dst], p1 = rowptr[dst + 1];
    for (int p = p0; p < p1; ++p) {
        int src = csr_src[p];                       // broadcast across 32 lanes
        float4 s0 = A4[src * 2 + 0];                // broadcast 32B
        float4 s1 = A4[src * 2 + 1];
        float e0 = s0.x + ad0.x, e1 = s0.y + ad0.y, e2 = s0.z + ad0.z, e3 = s0.w + ad0.w;
        float e4 = s1.x + ad1.x, e5 = s1.y + ad1.y, e6 = s1.z + ad1.z, e7 = s1.w + ad1.w;
        e0 = e0 > 0.f ? e0 : NEG_SLOPE * e0;  e1 = e1 > 0.f ? e1 : NEG_SLOPE * e1;
        e2 = e2 > 0.f ? e2 : NEG_SLOPE * e2;  e3 = e3 > 0.f ? e3 : NEG_SLOPE * e3;
        e4 = e4 > 0.f ? e4 : NEG_SLOPE * e4;  e5 = e5 > 0.f ? e5 : NEG_SLOPE * e5;
        e6 = e6 > 0.f ? e6 : NEG_SLOPE * e6;  e7 = e7 > 0.f ? e7 : NEG_SLOPE * e7;
        float w0 = __expf(e0), w1 = __expf(e1), w2 = __expf(e2), w3 = __expf(e3);
        float w4 = __expf(e4), w5 = __expf(e5), w6 = __expf(e6), w7 = __expf(e7);
        wsum[0] += w0; wsum[1] += w1; wsum[2] += w2; wsum[3] += w3;
        wsum[4] += w4; wsum[5] += w5; wsum[6] += w6; wsum[7] += w7;
        uint4 hv = H4[(size_t)src * 32 + c];        // 16B gather: 8 bf16 head-vals
        acc[0] += w0 * bflo(hv.x);  acc[1] += w1 * bfhi(hv.x);
        acc[2] += w2 * bflo(hv.y);  acc[3] += w3 * bfhi(hv.y);
        acc[4] += w4 * bflo(hv.z);  acc[5] += w5 * bfhi(hv.z);
        acc[6] += w6 * bflo(hv.w);  acc[7] += w7 * bfhi(hv.w);
    }
    float val = 0.f;
    #pragma unroll
    for (int h = 0; h < NHEAD; ++h) val += acc[h] / wsum[h];
    val = val * 0.125f + b[c];
    out[t] = val > 0.f ? val : (__expf(val) - 1.f);
}

// ================= output head: logits = h@Wo + bo, log_softmax (1 wave/node)
__global__ __launch_bounds__(64) void out_kernel(const float* __restrict__ hf,
        const float* __restrict__ Wo, const float* __restrict__ bo,
        float* __restrict__ out) {
    const int n = blockIdx.x;
    const int lane = threadIdx.x;
    __shared__ float hs[CH];
    if (lane < CH) hs[lane] = hf[n * CH + lane];
    __syncthreads();
    float logit = -INFINITY;
    if (lane < OUT_C) {
        float a = bo[lane];
        #pragma unroll
        for (int k = 0; k < CH; ++k) a += hs[k] * Wo[k * OUT_C + lane];
        logit = a;
    }
    float m = logit;
    #pragma unroll
    for (int off = 32; off; off >>= 1) m = fmaxf(m, __shfl_xor(m, off, 64));
    float ex = (lane < OUT_C) ? __expf(logit - m) : 0.f;
    float ssum = ex;
    #pragma unroll
    for (int off = 32; off; off >>= 1) ssum += __shfl_xor(ssum, off, 64);
    if (lane < OUT_C) out[(size_t)n * OUT_C + lane] = logit - m - __logf(ssum);
}

extern "C" void kernel_launch(void* const* d_in, const int* in_sizes, int n_in,
                              void* d_out, int out_size, void* d_ws, size_t ws_size,
                              hipStream_t stream) {
    const float* x      = (const float*)d_in[0];
    const int*   ei     = (const int*)  d_in[1];
    const float* W1     = (const float*)d_in[2];
    const float* a_src1 = (const float*)d_in[3];
    const float* a_dst1 = (const float*)d_in[4];
    const float* b1     = (const float*)d_in[5];
    const float* W2     = (const float*)d_in[6];
    const float* a_src2 = (const float*)d_in[7];
    const float* a_dst2 = (const float*)d_in[8];
    const float* b2     = (const float*)d_in[9];
    const float* Wo     = (const float*)d_in[10];
    const float* bo     = (const float*)d_in[11];
    float* out = (float*)d_out;

    // workspace carve-up (256B-aligned)
    char* ws = (char*)d_ws;
    size_t off = 0;
    auto carve = [&](size_t bytes) { char* p = ws + off; off += (bytes + 255) & ~(size_t)255; return p; };
    u16*   ht      = (u16*)  carve((size_t)N_NODES * HC * 2);      // 25.6 MB (bf16, transposed)
    u16*   xb      = (u16*)  carve((size_t)N_PAD * F_IN * 2);      // 25.6 MB (bf16 x, padded rows)
    u16*   Wt      = (u16*)  carve((size_t)HC * F_IN * 2);         // 128 KB (bf16 W1^T)
    float* asrc    = (float*)carve((size_t)N_NODES * NHEAD * 4);   // 1.6 MB
    float* adst    = (float*)carve((size_t)N_NODES * NHEAD * 4);
    float* hmid    = (float*)carve((size_t)N_NODES * CH * 4);      // 6.4 MB
    float* hout    = (float*)carve((size_t)N_NODES * CH * 4);      // 6.4 MB
    int*   deg     = (int*)  carve((size_t)N_NODES * 4);
    int*   rowptr  = (int*)  carve((size_t)(N_NODES + 1) * 4);
    int*   cursor  = (int*)  carve((size_t)N_NODES * 4);
    int*   csr_src = (int*)  carve((size_t)E_TOT * 4);             // 3.4 MB

    const int g_xcvt  = (N_NODES * F_IN / 8 + 255) / 256;    // 6250
    const int g_wcvt  = (HC * F_IN + 255) / 256;             // 256
    const int g_gemm1 = (N_NODES + 31) / 32;                 // 1563
    const int g_gemm2 = (N_NODES + G2_ROWS - 1) / G2_ROWS;   // 391
    const int g_nh    = (N_NODES * NHEAD + 255) / 256;       // 1563
    const int g_edge  = (E_TOT + 255) / 256;                 // 3321
    const int g_attn  = (N_NODES * CH + 255) / 256;          // 6250

    // ---------- prep + CSR build ----------
    xcvt_kernel<<<g_xcvt, 256, 0, stream>>>(x, xb);
    wcvt_kernel<<<g_wcvt, 256, 0, stream>>>(W1, Wt);
    hipMemsetAsync(deg, 0, (size_t)N_NODES * 4, stream);
    deg_kernel<<<g_edge, 256, 0, stream>>>(ei, deg);
    scan_kernel<<<1, 1024, 0, stream>>>(deg, rowptr, cursor);
    scatter_kernel<<<g_edge, 256, 0, stream>>>(ei, cursor, csr_src);

    // ---------- layer 1 ----------
    gemm1_mfma<<<g_gemm1, 256, 0, stream>>>(xb, Wt, ht);
    alpha_t_kernel<<<g_nh, 256, 0, stream>>>(ht, a_src1, a_dst1, asrc, adst);
    attn_kernel<<<g_attn, 256, 0, stream>>>(rowptr, csr_src, asrc, adst, ht, b1, hmid);

    // ---------- layer 2 ----------
    gemm2_kernel<<<g_gemm2, 256, 0, stream>>>(hmid, W2, ht, a_src2, a_dst2, asrc, adst);
    attn_kernel<<<g_attn, 256, 0, stream>>>(rowptr, csr_src, asrc, adst, ht, b2, hout);

    // ---------- output head ----------
    out_kernel<<<N_NODES, 64, 0, stream>>>(hout, Wo, bo, out);
}

// Round 10
// 539.991 us; speedup vs baseline: 3.6102x; 1.2252x over previous
//
#include <hip/hip_runtime.h>
#include <math.h>

#define N_NODES 50000
#define N_PAD   50016                 // padded to 32-row gemm tiles
#define N_EDGES 800000
#define E_TOT   (N_EDGES + N_NODES)   // edges + self-loops = 850000
#define F_IN    256
#define NHEAD   8
#define CH      32
#define HC      256                   // NHEAD*CH
#define OUT_C   40
#define NEG_SLOPE 0.2f
#define SCAN_BLOCKS ((N_NODES + 255) / 256)   // 196

typedef unsigned short u16;
typedef unsigned int   u32;
typedef __attribute__((ext_vector_type(8))) short bf16x8;   // 4 VGPRs
typedef __attribute__((ext_vector_type(4))) float f32x4;

__device__ __forceinline__ u16 f2bf(float f) {
    union { u32 u; float f; } x; x.f = f;
    u32 u = x.u;
    return (u16)((u + 0x7fffu + ((u >> 16) & 1u)) >> 16);   // round-nearest-even
}
__device__ __forceinline__ float bflo(u32 v) {
    union { u32 u; float f; } x; x.u = v << 16; return x.f;
}
__device__ __forceinline__ float bfhi(u32 v) {
    union { u32 u; float f; } x; x.u = v & 0xffff0000u; return x.f;
}

// ht is bf16, TRANSPOSED per node: ht[node*256 + c*8 + hd] -> the 8 head-values
// of channel c are 16 contiguous bytes (one uint4 gather in attn_kernel).

// ================= prep: x -> bf16 (row layout unchanged)
__global__ __launch_bounds__(256) void xcvt_kernel(const float* __restrict__ x,
        u16* __restrict__ xb) {
    int t = blockIdx.x * 256 + threadIdx.x;          // one per 8 elements
    if (t >= N_NODES * F_IN / 8) return;
    const float4* xp = (const float4*)x + (size_t)t * 2;
    float4 v0 = xp[0], v1 = xp[1];
    uint4 o;
    o.x = (u32)f2bf(v0.x) | ((u32)f2bf(v0.y) << 16);
    o.y = (u32)f2bf(v0.z) | ((u32)f2bf(v0.w) << 16);
    o.z = (u32)f2bf(v1.x) | ((u32)f2bf(v1.y) << 16);
    o.w = (u32)f2bf(v1.z) | ((u32)f2bf(v1.w) << 16);
    ((uint4*)xb)[t] = o;
}

// ================= prep: Wt[n][k] = bf16(W1[k][n])  (transpose for B-frags)
__global__ __launch_bounds__(256) void wcvt_kernel(const float* __restrict__ W,
        u16* __restrict__ Wt) {
    int t = blockIdx.x * 256 + threadIdx.x;          // 65536 total
    int n = t & 255, k = t >> 8;                     // coalesced reads
    Wt[(size_t)n * F_IN + k] = f2bf(W[(size_t)k * HC + n]);
}

// ================= GEMM1 via MFMA bf16: ht = bf16(x @ W1), transposed store
// Block: 32 rows x 256 cols, 4 waves; wave w -> cols w*64..+63.
// Wave: 2 M-tiles x 4 N-tiles of 16x16, K=256 in 8 steps of 32.
// Frags (verified layouts): A[m=lane&15][k=quad*8+j]; B from Wt[n][k] (n=lane&15);
// C/D: col=lane&15, row=quad*4+reg. No LDS; frag loads are 16B global (L1/L2).
__global__ __launch_bounds__(256) void gemm1_mfma(const u16* __restrict__ xb,
        const u16* __restrict__ Wt, u16* __restrict__ ht) {
    const int row0 = blockIdx.x * 32;
    const int t    = threadIdx.x;
    const int wave = t >> 6;
    const int lane = t & 63;
    const int l16  = lane & 15;
    const int quad = lane >> 4;
    const int nb   = wave * 64;

    f32x4 acc[2][4];
    #pragma unroll
    for (int m = 0; m < 2; ++m)
        #pragma unroll
        for (int n = 0; n < 4; ++n) acc[m][n] = (f32x4){0.f, 0.f, 0.f, 0.f};

    const u16* a0p = xb + (size_t)(row0 + l16) * F_IN;        // M-tile 0
    const u16* a1p = a0p + 16 * F_IN;                         // M-tile 1
    const u16* bp  = Wt + (size_t)(nb + l16) * F_IN;          // N-tile stride 16*F_IN

    #pragma unroll 1
    for (int k0 = 0; k0 < F_IN; k0 += 32) {
        const int ko = k0 + quad * 8;
        bf16x8 a0 = *(const bf16x8*)(a0p + ko);
        bf16x8 a1 = *(const bf16x8*)(a1p + ko);
        bf16x8 b0 = *(const bf16x8*)(bp + 0 * 16 * F_IN + ko);
        bf16x8 b1 = *(const bf16x8*)(bp + 1 * 16 * F_IN + ko);
        bf16x8 b2 = *(const bf16x8*)(bp + 2 * 16 * F_IN + ko);
        bf16x8 b3 = *(const bf16x8*)(bp + 3 * 16 * F_IN + ko);
        acc[0][0] = __builtin_amdgcn_mfma_f32_16x16x32_bf16(a0, b0, acc[0][0], 0, 0, 0);
        acc[0][1] = __builtin_amdgcn_mfma_f32_16x16x32_bf16(a0, b1, acc[0][1], 0, 0, 0);
        acc[0][2] = __builtin_amdgcn_mfma_f32_16x16x32_bf16(a0, b2, acc[0][2], 0, 0, 0);
        acc[0][3] = __builtin_amdgcn_mfma_f32_16x16x32_bf16(a0, b3, acc[0][3], 0, 0, 0);
        acc[1][0] = __builtin_amdgcn_mfma_f32_16x16x32_bf16(a1, b0, acc[1][0], 0, 0, 0);
        acc[1][1] = __builtin_amdgcn_mfma_f32_16x16x32_bf16(a1, b1, acc[1][1], 0, 0, 0);
        acc[1][2] = __builtin_amdgcn_mfma_f32_16x16x32_bf16(a1, b2, acc[1][2], 0, 0, 0);
        acc[1][3] = __builtin_amdgcn_mfma_f32_16x16x32_bf16(a1, b3, acc[1][3], 0, 0, 0);
    }

    #pragma unroll
    for (int m = 0; m < 2; ++m) {
        #pragma unroll
        for (int r = 0; r < 4; ++r) {
            int row = row0 + m * 16 + quad * 4 + r;
            if (row < N_NODES) {
                u16* hr = ht + (size_t)row * HC;
                #pragma unroll
                for (int n = 0; n < 4; ++n) {
                    int col = nb + n * 16 + l16;
                    int hd = col >> 5, cc = col & 31;
                    hr[cc * 8 + hd] = f2bf(acc[m][n][r]);
                }
            }
        }
    }
}

// ================= alpha from transposed bf16 ht: asrc/adst [N,8]
__global__ __launch_bounds__(256) void alpha_t_kernel(const u16* __restrict__ ht,
        const float* __restrict__ a_src, const float* __restrict__ a_dst,
        float* __restrict__ asrc, float* __restrict__ adst) {
    int t = blockIdx.x * 256 + threadIdx.x;
    if (t >= N_NODES * NHEAD) return;
    int node = t >> 3;
    int hd   = t & 7;
    const u16* hp = ht + (size_t)node * HC + hd;
    const float* ap = a_src + hd * CH;
    const float* dp = a_dst + hd * CH;
    float s1 = 0.f, s2 = 0.f;
    #pragma unroll
    for (int c = 0; c < CH; ++c) {
        float hv = bflo((u32)hp[c * 8]);
        s1 += hv * ap[c];
        s2 += hv * dp[c];
    }
    asrc[t] = s1;
    adst[t] = s2;
}

// ================= GEMM2 + fused alpha: ht = bf16(hm @ W2) (transposed store)
#define G2_ROWS 128
__global__ __launch_bounds__(256) void gemm2_kernel(const float* __restrict__ hm,
        const float* __restrict__ W, u16* __restrict__ ht,
        const float* __restrict__ a_src, const float* __restrict__ a_dst,
        float* __restrict__ asrc, float* __restrict__ adst) {
    const int row0 = blockIdx.x * G2_ROWS;
    const int c  = threadIdx.x;
    const int hd = c >> 5;
    const int cc = c & 31;
    float w[CH];
    #pragma unroll
    for (int k = 0; k < CH; ++k) w[k] = W[k * HC + c];
    const float as = a_src[hd * CH + cc];
    const float ad = a_dst[hd * CH + cc];
    for (int i = 0; i < G2_ROWS; ++i) {
        int row = row0 + i;
        if (row >= N_NODES) break;                 // uniform
        const float* hr = hm + (size_t)row * CH;   // block-uniform -> scalar loads
        float a = 0.f;
        #pragma unroll
        for (int k = 0; k < CH; ++k) a += hr[k] * w[k];
        ht[(size_t)row * HC + cc * 8 + hd] = f2bf(a);
        float ps = a * as, pd = a * ad;
        #pragma unroll
        for (int off = 1; off < 32; off <<= 1) {
            ps += __shfl_xor(ps, off, 64);
            pd += __shfl_xor(pd, off, 64);
        }
        if (cc == 0) {
            asrc[row * NHEAD + hd] = ps;
            adst[row * NHEAD + hd] = pd;
        }
    }
}

// ================= CSR build =================
__global__ __launch_bounds__(256) void deg_kernel(const int* __restrict__ ei,
        int* __restrict__ deg) {
    int j = blockIdx.x * 256 + threadIdx.x;
    if (j >= E_TOT) return;
    int dst = (j < N_EDGES) ? ei[N_EDGES + j] : (j - N_EDGES);
    atomicAdd(&deg[dst], 1);
}

// -------- parallel 3-phase exclusive scan of deg -> rowptr/cursor
// (r9 post-mortem: single-block scan was 126us, VALUBusy 0.01% — pure latency)
__device__ __forceinline__ int wave_incl_scan(int v, int lane) {
    #pragma unroll
    for (int d = 1; d < 64; d <<= 1) {
        int u = __shfl_up(v, d, 64);
        if (lane >= d) v += u;
    }
    return v;
}

// phase 1: per-block scan of 256-elt chunk; local exclusive -> rowptr, total -> partials
__global__ __launch_bounds__(256) void scan1_kernel(const int* __restrict__ deg,
        int* __restrict__ rowptr, int* __restrict__ partials) {
    const int t    = blockIdx.x * 256 + threadIdx.x;
    const int lane = threadIdx.x & 63;
    const int wid  = threadIdx.x >> 6;
    int v = (t < N_NODES) ? deg[t] : 0;
    int inc = wave_incl_scan(v, lane);
    __shared__ int wtot[4];
    if (lane == 63) wtot[wid] = inc;
    __syncthreads();
    int woff = 0;
    #pragma unroll
    for (int i = 0; i < 4; ++i) woff += (i < wid) ? wtot[i] : 0;
    if (t < N_NODES) rowptr[t] = inc - v + woff;      // block-local exclusive
    if (threadIdx.x == 255) partials[blockIdx.x] = woff + inc;  // block total
}

// phase 2: one block scans the 196 block totals in place (exclusive)
__global__ __launch_bounds__(256) void scan2_kernel(int* __restrict__ partials) {
    const int t    = threadIdx.x;
    const int lane = t & 63;
    const int wid  = t >> 6;
    int v = (t < SCAN_BLOCKS) ? partials[t] : 0;
    int inc = wave_incl_scan(v, lane);
    __shared__ int wtot[4];
    if (lane == 63) wtot[wid] = inc;
    __syncthreads();
    int woff = 0;
    #pragma unroll
    for (int i = 0; i < 4; ++i) woff += (i < wid) ? wtot[i] : 0;
    __syncthreads();
    if (t < SCAN_BLOCKS) partials[t] = inc - v + woff;
}

// phase 3: add block offsets; copy to cursor; cap rowptr[N]
__global__ __launch_bounds__(256) void scan3_kernel(int* __restrict__ rowptr,
        int* __restrict__ cursor, const int* __restrict__ partials) {
    const int t = blockIdx.x * 256 + threadIdx.x;
    if (t < N_NODES) {
        int v = rowptr[t] + partials[blockIdx.x];
        rowptr[t] = v;
        cursor[t] = v;
    } else if (t == N_NODES) {
        rowptr[N_NODES] = E_TOT;
    }
}

__global__ __launch_bounds__(256) void scatter_kernel(const int* __restrict__ ei,
        int* __restrict__ cursor, int* __restrict__ csr_src) {
    int j = blockIdx.x * 256 + threadIdx.x;
    if (j >= E_TOT) return;
    int src, dst;
    if (j < N_EDGES) { src = ei[j]; dst = ei[N_EDGES + j]; }
    else             { src = j - N_EDGES; dst = src; }
    int pos = atomicAdd(&cursor[dst], 1);
    csr_src[pos] = src;
}

// ================= fused attention: softmax + aggregate in ONE pass
__global__ __launch_bounds__(256) void attn_kernel(const int* __restrict__ rowptr,
        const int* __restrict__ csr_src, const float* __restrict__ asrc,
        const float* __restrict__ adst, const u16* __restrict__ ht,
        const float* __restrict__ b, float* __restrict__ out) {
    int t = blockIdx.x * 256 + threadIdx.x;
    if (t >= N_NODES * CH) return;
    int dst = t >> 5;
    int c   = t & 31;
    const float4* A4 = (const float4*)asrc;
    const float4 ad0 = ((const float4*)adst)[dst * 2 + 0];   // broadcast
    const float4 ad1 = ((const float4*)adst)[dst * 2 + 1];
    const uint4* H4 = (const uint4*)ht;   // row = 32 uint4; lane c reads uint4 #c

    float acc[NHEAD], wsum[NHEAD];
    #pragma unroll
    for (int h = 0; h < NHEAD; ++h) { acc[h] = 0.f; wsum[h] = 0.f; }

    int p0 = rowptr[dst], p1 = rowptr[dst + 1];
    for (int p = p0; p < p1; ++p) {
        int src = csr_src[p];                       // broadcast across 32 lanes
        float4 s0 = A4[src * 2 + 0];                // broadcast 32B
        float4 s1 = A4[src * 2 + 1];
        float e0 = s0.x + ad0.x, e1 = s0.y + ad0.y, e2 = s0.z + ad0.z, e3 = s0.w + ad0.w;
        float e4 = s1.x + ad1.x, e5 = s1.y + ad1.y, e6 = s1.z + ad1.z, e7 = s1.w + ad1.w;
        e0 = e0 > 0.f ? e0 : NEG_SLOPE * e0;  e1 = e1 > 0.f ? e1 : NEG_SLOPE * e1;
        e2 = e2 > 0.f ? e2 : NEG_SLOPE * e2;  e3 = e3 > 0.f ? e3 : NEG_SLOPE * e3;
        e4 = e4 > 0.f ? e4 : NEG_SLOPE * e4;  e5 = e5 > 0.f ? e5 : NEG_SLOPE * e5;
        e6 = e6 > 0.f ? e6 : NEG_SLOPE * e6;  e7 = e7 > 0.f ? e7 : NEG_SLOPE * e7;
        float w0 = __expf(e0), w1 = __expf(e1), w2 = __expf(e2), w3 = __expf(e3);
        float w4 = __expf(e4), w5 = __expf(e5), w6 = __expf(e6), w7 = __expf(e7);
        wsum[0] += w0; wsum[1] += w1; wsum[2] += w2; wsum[3] += w3;
        wsum[4] += w4; wsum[5] += w5; wsum[6] += w6; wsum[7] += w7;
        uint4 hv = H4[(size_t)src * 32 + c];        // 16B gather: 8 bf16 head-vals
        acc[0] += w0 * bflo(hv.x);  acc[1] += w1 * bfhi(hv.x);
        acc[2] += w2 * bflo(hv.y);  acc[3] += w3 * bfhi(hv.y);
        acc[4] += w4 * bflo(hv.z);  acc[5] += w5 * bfhi(hv.z);
        acc[6] += w6 * bflo(hv.w);  acc[7] += w7 * bfhi(hv.w);
    }
    float val = 0.f;
    #pragma unroll
    for (int h = 0; h < NHEAD; ++h) val += acc[h] / wsum[h];
    val = val * 0.125f + b[c];
    out[t] = val > 0.f ? val : (__expf(val) - 1.f);
}

// ================= output head: logits = h@Wo + bo, log_softmax (1 wave/node)
__global__ __launch_bounds__(64) void out_kernel(const float* __restrict__ hf,
        const float* __restrict__ Wo, const float* __restrict__ bo,
        float* __restrict__ out) {
    const int n = blockIdx.x;
    const int lane = threadIdx.x;
    __shared__ float hs[CH];
    if (lane < CH) hs[lane] = hf[n * CH + lane];
    __syncthreads();
    float logit = -INFINITY;
    if (lane < OUT_C) {
        float a = bo[lane];
        #pragma unroll
        for (int k = 0; k < CH; ++k) a += hs[k] * Wo[k * OUT_C + lane];
        logit = a;
    }
    float m = logit;
    #pragma unroll
    for (int off = 32; off; off >>= 1) m = fmaxf(m, __shfl_xor(m, off, 64));
    float ex = (lane < OUT_C) ? __expf(logit - m) : 0.f;
    float ssum = ex;
    #pragma unroll
    for (int off = 32; off; off >>= 1) ssum += __shfl_xor(ssum, off, 64);
    if (lane < OUT_C) out[(size_t)n * OUT_C + lane] = logit - m - __logf(ssum);
}

extern "C" void kernel_launch(void* const* d_in, const int* in_sizes, int n_in,
                              void* d_out, int out_size, void* d_ws, size_t ws_size,
                              hipStream_t stream) {
    const float* x      = (const float*)d_in[0];
    const int*   ei     = (const int*)  d_in[1];
    const float* W1     = (const float*)d_in[2];
    const float* a_src1 = (const float*)d_in[3];
    const float* a_dst1 = (const float*)d_in[4];
    const float* b1     = (const float*)d_in[5];
    const float* W2     = (const float*)d_in[6];
    const float* a_src2 = (const float*)d_in[7];
    const float* a_dst2 = (const float*)d_in[8];
    const float* b2     = (const float*)d_in[9];
    const float* Wo     = (const float*)d_in[10];
    const float* bo     = (const float*)d_in[11];
    float* out = (float*)d_out;

    // workspace carve-up (256B-aligned)
    char* ws = (char*)d_ws;
    size_t off = 0;
    auto carve = [&](size_t bytes) { char* p = ws + off; off += (bytes + 255) & ~(size_t)255; return p; };
    u16*   ht      = (u16*)  carve((size_t)N_NODES * HC * 2);      // 25.6 MB (bf16, transposed)
    u16*   xb      = (u16*)  carve((size_t)N_PAD * F_IN * 2);      // 25.6 MB (bf16 x, padded rows)
    u16*   Wt      = (u16*)  carve((size_t)HC * F_IN * 2);         // 128 KB (bf16 W1^T)
    float* asrc    = (float*)carve((size_t)N_NODES * NHEAD * 4);   // 1.6 MB
    float* adst    = (float*)carve((size_t)N_NODES * NHEAD * 4);
    float* hmid    = (float*)carve((size_t)N_NODES * CH * 4);      // 6.4 MB
    float* hout    = (float*)carve((size_t)N_NODES * CH * 4);      // 6.4 MB
    int*   deg     = (int*)  carve((size_t)N_NODES * 4);
    int*   rowptr  = (int*)  carve((size_t)(N_NODES + 1) * 4);
    int*   cursor  = (int*)  carve((size_t)N_NODES * 4);
    int*   csr_src = (int*)  carve((size_t)E_TOT * 4);             // 3.4 MB
    int*   partials= (int*)  carve((size_t)SCAN_BLOCKS * 4);

    const int g_xcvt  = (N_NODES * F_IN / 8 + 255) / 256;    // 6250
    const int g_wcvt  = (HC * F_IN + 255) / 256;             // 256
    const int g_gemm1 = (N_NODES + 31) / 32;                 // 1563
    const int g_gemm2 = (N_NODES + G2_ROWS - 1) / G2_ROWS;   // 391
    const int g_nh    = (N_NODES * NHEAD + 255) / 256;       // 1563
    const int g_edge  = (E_TOT + 255) / 256;                 // 3321
    const int g_attn  = (N_NODES * CH + 255) / 256;          // 6250

    // ---------- prep + CSR build ----------
    xcvt_kernel<<<g_xcvt, 256, 0, stream>>>(x, xb);
    wcvt_kernel<<<g_wcvt, 256, 0, stream>>>(W1, Wt);
    hipMemsetAsync(deg, 0, (size_t)N_NODES * 4, stream);
    deg_kernel<<<g_edge, 256, 0, stream>>>(ei, deg);
    scan1_kernel<<<SCAN_BLOCKS, 256, 0, stream>>>(deg, rowptr, partials);
    scan2_kernel<<<1, 256, 0, stream>>>(partials);
    scan3_kernel<<<SCAN_BLOCKS, 256, 0, stream>>>(rowptr, cursor, partials);
    scatter_kernel<<<g_edge, 256, 0, stream>>>(ei, cursor, csr_src);

    // ---------- layer 1 ----------
    gemm1_mfma<<<g_gemm1, 256, 0, stream>>>(xb, Wt, ht);
    alpha_t_kernel<<<g_nh, 256, 0, stream>>>(ht, a_src1, a_dst1, asrc, adst);
    attn_kernel<<<g_attn, 256, 0, stream>>>(rowptr, csr_src, asrc, adst, ht, b1, hmid);

    // ---------- layer 2 ----------
    gemm2_kernel<<<g_gemm2, 256, 0, stream>>>(hmid, W2, ht, a_src2, a_dst2, asrc, adst);
    attn_kernel<<<g_attn, 256, 0, stream>>>(rowptr, csr_src, asrc, adst, ht, b2, hout);

    // ---------- output head ----------
    out_kernel<<<N_NODES, 64, 0, stream>>>(hout, Wo, bo, out);
}

// Round 12
// 531.593 us; speedup vs baseline: 3.6672x; 1.0158x over previous
//
#include <hip/hip_runtime.h>
#include <math.h>

#define N_NODES 50000
#define N_PAD   50016                 // padded to 32-row gemm tiles
#define N_EDGES 800000
#define E_TOT   (N_EDGES + N_NODES)   // edges + self-loops = 850000
#define F_IN    256
#define NHEAD   8
#define CH      32
#define HC      256                   // NHEAD*CH
#define OUT_C   40
#define NEG_SLOPE 0.2f
#define SCAN_BLOCKS ((N_NODES + 255) / 256)   // 196

typedef unsigned short u16;
typedef unsigned int   u32;
typedef __attribute__((ext_vector_type(8))) short bf16x8;   // 4 VGPRs
typedef __attribute__((ext_vector_type(4))) float f32x4;

__device__ __forceinline__ u16 f2bf(float f) {
    union { u32 u; float f; } x; x.f = f;
    u32 u = x.u;
    return (u16)((u + 0x7fffu + ((u >> 16) & 1u)) >> 16);   // round-nearest-even
}
__device__ __forceinline__ float bflo(u32 v) {
    union { u32 u; float f; } x; x.u = v << 16; return x.f;
}
__device__ __forceinline__ float bfhi(u32 v) {
    union { u32 u; float f; } x; x.u = v & 0xffff0000u; return x.f;
}
// broadcast-from-head-owner within each 8-lane group (BitMode: and=0x18, or=H)
// NOTE r11: ds_swizzle pattern must be an integral constant EXPRESSION at the
// call site -> template parameter, not a function argument.
template <int H>
__device__ __forceinline__ float swz_head(float v) {
    return __int_as_float(__builtin_amdgcn_ds_swizzle(__float_as_int(v),
                                                      (H << 5) | 0x18));
}

// ht is bf16, TRANSPOSED per node: ht[node*256 + c*8 + hd] -> the 8 head-values
// of channel c are 16 contiguous bytes (one uint4 gather in attn_kernel).

// ================= prep: x -> bf16 (row layout unchanged)
__global__ __launch_bounds__(256) void xcvt_kernel(const float* __restrict__ x,
        u16* __restrict__ xb) {
    int t = blockIdx.x * 256 + threadIdx.x;          // one per 8 elements
    if (t >= N_NODES * F_IN / 8) return;
    const float4* xp = (const float4*)x + (size_t)t * 2;
    float4 v0 = xp[0], v1 = xp[1];
    uint4 o;
    o.x = (u32)f2bf(v0.x) | ((u32)f2bf(v0.y) << 16);
    o.y = (u32)f2bf(v0.z) | ((u32)f2bf(v0.w) << 16);
    o.z = (u32)f2bf(v1.x) | ((u32)f2bf(v1.y) << 16);
    o.w = (u32)f2bf(v1.z) | ((u32)f2bf(v1.w) << 16);
    ((uint4*)xb)[t] = o;
}

// ================= prep: Wt[n][k] = bf16(W1[k][n])  (transpose for B-frags)
__global__ __launch_bounds__(256) void wcvt_kernel(const float* __restrict__ W,
        u16* __restrict__ Wt) {
    int t = blockIdx.x * 256 + threadIdx.x;          // 65536 total
    int n = t & 255, k = t >> 8;                     // coalesced reads
    Wt[(size_t)n * F_IN + k] = f2bf(W[(size_t)k * HC + n]);
}

// ================= GEMM1 via MFMA bf16: ht = bf16(x @ W1), transposed store
// Frags (verified): A[m=lane&15][k=quad*8+j]; B from Wt[n][k]; C/D col=lane&15,
// row=quad*4+reg. No LDS; frag loads are 16B global (L1/L2-resident).
__global__ __launch_bounds__(256) void gemm1_mfma(const u16* __restrict__ xb,
        const u16* __restrict__ Wt, u16* __restrict__ ht) {
    const int row0 = blockIdx.x * 32;
    const int t    = threadIdx.x;
    const int wave = t >> 6;
    const int lane = t & 63;
    const int l16  = lane & 15;
    const int quad = lane >> 4;
    const int nb   = wave * 64;

    f32x4 acc[2][4];
    #pragma unroll
    for (int m = 0; m < 2; ++m)
        #pragma unroll
        for (int n = 0; n < 4; ++n) acc[m][n] = (f32x4){0.f, 0.f, 0.f, 0.f};

    const u16* a0p = xb + (size_t)(row0 + l16) * F_IN;        // M-tile 0
    const u16* a1p = a0p + 16 * F_IN;                         // M-tile 1
    const u16* bp  = Wt + (size_t)(nb + l16) * F_IN;          // N-tile stride 16*F_IN

    #pragma unroll 1
    for (int k0 = 0; k0 < F_IN; k0 += 32) {
        const int ko = k0 + quad * 8;
        bf16x8 a0 = *(const bf16x8*)(a0p + ko);
        bf16x8 a1 = *(const bf16x8*)(a1p + ko);
        bf16x8 b0 = *(const bf16x8*)(bp + 0 * 16 * F_IN + ko);
        bf16x8 b1 = *(const bf16x8*)(bp + 1 * 16 * F_IN + ko);
        bf16x8 b2 = *(const bf16x8*)(bp + 2 * 16 * F_IN + ko);
        bf16x8 b3 = *(const bf16x8*)(bp + 3 * 16 * F_IN + ko);
        acc[0][0] = __builtin_amdgcn_mfma_f32_16x16x32_bf16(a0, b0, acc[0][0], 0, 0, 0);
        acc[0][1] = __builtin_amdgcn_mfma_f32_16x16x32_bf16(a0, b1, acc[0][1], 0, 0, 0);
        acc[0][2] = __builtin_amdgcn_mfma_f32_16x16x32_bf16(a0, b2, acc[0][2], 0, 0, 0);
        acc[0][3] = __builtin_amdgcn_mfma_f32_16x16x32_bf16(a0, b3, acc[0][3], 0, 0, 0);
        acc[1][0] = __builtin_amdgcn_mfma_f32_16x16x32_bf16(a1, b0, acc[1][0], 0, 0, 0);
        acc[1][1] = __builtin_amdgcn_mfma_f32_16x16x32_bf16(a1, b1, acc[1][1], 0, 0, 0);
        acc[1][2] = __builtin_amdgcn_mfma_f32_16x16x32_bf16(a1, b2, acc[1][2], 0, 0, 0);
        acc[1][3] = __builtin_amdgcn_mfma_f32_16x16x32_bf16(a1, b3, acc[1][3], 0, 0, 0);
    }

    #pragma unroll
    for (int m = 0; m < 2; ++m) {
        #pragma unroll
        for (int r = 0; r < 4; ++r) {
            int row = row0 + m * 16 + quad * 4 + r;
            if (row < N_NODES) {
                u16* hr = ht + (size_t)row * HC;
                #pragma unroll
                for (int n = 0; n < 4; ++n) {
                    int col = nb + n * 16 + l16;
                    int hd = col >> 5, cc = col & 31;
                    hr[cc * 8 + hd] = f2bf(acc[m][n][r]);
                }
            }
        }
    }
}

// ================= alpha from transposed bf16 ht: asrc/adst [N,8]
__global__ __launch_bounds__(256) void alpha_t_kernel(const u16* __restrict__ ht,
        const float* __restrict__ a_src, const float* __restrict__ a_dst,
        float* __restrict__ asrc, float* __restrict__ adst) {
    int t = blockIdx.x * 256 + threadIdx.x;
    if (t >= N_NODES * NHEAD) return;
    int node = t >> 3;
    int hd   = t & 7;
    const u16* hp = ht + (size_t)node * HC + hd;
    const float* ap = a_src + hd * CH;
    const float* dp = a_dst + hd * CH;
    float s1 = 0.f, s2 = 0.f;
    #pragma unroll
    for (int c = 0; c < CH; ++c) {
        float hv = bflo((u32)hp[c * 8]);
        s1 += hv * ap[c];
        s2 += hv * dp[c];
    }
    asrc[t] = s1;
    adst[t] = s2;
}

// ================= GEMM2 + fused alpha: ht = bf16(hm @ W2) (transposed store)
#define G2_ROWS 128
__global__ __launch_bounds__(256) void gemm2_kernel(const float* __restrict__ hm,
        const float* __restrict__ W, u16* __restrict__ ht,
        const float* __restrict__ a_src, const float* __restrict__ a_dst,
        float* __restrict__ asrc, float* __restrict__ adst) {
    const int row0 = blockIdx.x * G2_ROWS;
    const int c  = threadIdx.x;
    const int hd = c >> 5;
    const int cc = c & 31;
    float w[CH];
    #pragma unroll
    for (int k = 0; k < CH; ++k) w[k] = W[k * HC + c];
    const float as = a_src[hd * CH + cc];
    const float ad = a_dst[hd * CH + cc];
    for (int i = 0; i < G2_ROWS; ++i) {
        int row = row0 + i;
        if (row >= N_NODES) break;                 // uniform
        const float* hr = hm + (size_t)row * CH;   // block-uniform -> scalar loads
        float a = 0.f;
        #pragma unroll
        for (int k = 0; k < CH; ++k) a += hr[k] * w[k];
        ht[(size_t)row * HC + cc * 8 + hd] = f2bf(a);
        float ps = a * as, pd = a * ad;
        #pragma unroll
        for (int off = 1; off < 32; off <<= 1) {
            ps += __shfl_xor(ps, off, 64);
            pd += __shfl_xor(pd, off, 64);
        }
        if (cc == 0) {
            asrc[row * NHEAD + hd] = ps;
            adst[row * NHEAD + hd] = pd;
        }
    }
}

// ================= CSR build =================
__global__ __launch_bounds__(256) void deg_kernel(const int* __restrict__ ei,
        int* __restrict__ deg) {
    int j = blockIdx.x * 256 + threadIdx.x;
    if (j >= E_TOT) return;
    int dst = (j < N_EDGES) ? ei[N_EDGES + j] : (j - N_EDGES);
    atomicAdd(&deg[dst], 1);
}

// -------- parallel 3-phase exclusive scan of deg -> rowptr/cursor
__device__ __forceinline__ int wave_incl_scan(int v, int lane) {
    #pragma unroll
    for (int d = 1; d < 64; d <<= 1) {
        int u = __shfl_up(v, d, 64);
        if (lane >= d) v += u;
    }
    return v;
}

__global__ __launch_bounds__(256) void scan1_kernel(const int* __restrict__ deg,
        int* __restrict__ rowptr, int* __restrict__ partials) {
    const int t    = blockIdx.x * 256 + threadIdx.x;
    const int lane = threadIdx.x & 63;
    const int wid  = threadIdx.x >> 6;
    int v = (t < N_NODES) ? deg[t] : 0;
    int inc = wave_incl_scan(v, lane);
    __shared__ int wtot[4];
    if (lane == 63) wtot[wid] = inc;
    __syncthreads();
    int woff = 0;
    #pragma unroll
    for (int i = 0; i < 4; ++i) woff += (i < wid) ? wtot[i] : 0;
    if (t < N_NODES) rowptr[t] = inc - v + woff;      // block-local exclusive
    if (threadIdx.x == 255) partials[blockIdx.x] = woff + inc;  // block total
}

__global__ __launch_bounds__(256) void scan2_kernel(int* __restrict__ partials) {
    const int t    = threadIdx.x;
    const int lane = t & 63;
    const int wid  = t >> 6;
    int v = (t < SCAN_BLOCKS) ? partials[t] : 0;
    int inc = wave_incl_scan(v, lane);
    __shared__ int wtot[4];
    if (lane == 63) wtot[wid] = inc;
    __syncthreads();
    int woff = 0;
    #pragma unroll
    for (int i = 0; i < 4; ++i) woff += (i < wid) ? wtot[i] : 0;
    __syncthreads();
    if (t < SCAN_BLOCKS) partials[t] = inc - v + woff;
}

__global__ __launch_bounds__(256) void scan3_kernel(int* __restrict__ rowptr,
        int* __restrict__ cursor, const int* __restrict__ partials) {
    const int t = blockIdx.x * 256 + threadIdx.x;
    if (t < N_NODES) {
        int v = rowptr[t] + partials[blockIdx.x];
        rowptr[t] = v;
        cursor[t] = v;
    } else if (t == N_NODES) {
        rowptr[N_NODES] = E_TOT;
    }
}

__global__ __launch_bounds__(256) void scatter_kernel(const int* __restrict__ ei,
        int* __restrict__ cursor, int* __restrict__ csr_src) {
    int j = blockIdx.x * 256 + threadIdx.x;
    if (j >= E_TOT) return;
    int src, dst;
    if (j < N_EDGES) { src = ei[j]; dst = ei[N_EDGES + j]; }
    else             { src = j - N_EDGES; dst = src; }
    int pos = atomicAdd(&cursor[dst], 1);
    csr_src[pos] = src;
}

// ================= fused attention: softmax + aggregate in ONE pass
// r10 post-mortem: 93us, VALUBusy 73% — 32 lanes redundantly computed the same
// 8 exps per edge (trans pipe, quarter rate). Now lane l computes ONLY head
// (l&7)'s exp; 8 ds_swizzle ops (DS pipe, off-VALU) distribute w0..w7.
// All lanes of a 32-group are uniformly active (same dst) -> swizzle-safe.
__global__ __launch_bounds__(256) void attn_kernel(const int* __restrict__ rowptr,
        const int* __restrict__ csr_src, const float* __restrict__ asrc,
        const float* __restrict__ adst, const u16* __restrict__ ht,
        const float* __restrict__ b, float* __restrict__ out) {
    int t = blockIdx.x * 256 + threadIdx.x;
    if (t >= N_NODES * CH) return;
    int dst = t >> 5;
    int c   = t & 31;
    int hown = c & 7;                               // this lane's owned head
    const float ad_own = adst[dst * NHEAD + hown];
    const uint4* H4 = (const uint4*)ht;   // row = 32 uint4; lane c reads uint4 #c

    float acc[NHEAD];
    #pragma unroll
    for (int h = 0; h < NHEAD; ++h) acc[h] = 0.f;
    float wsum_own = 0.f;

    int p0 = rowptr[dst], p1 = rowptr[dst + 1];
    for (int p = p0; p < p1; ++p) {
        int src = csr_src[p];                       // broadcast across 32 lanes
        float e = asrc[src * NHEAD + hown] + ad_own;   // own head only
        e = e > 0.f ? e : NEG_SLOPE * e;
        float w = __expf(e);                        // ONE exp per lane
        wsum_own += w;
        float w0 = swz_head<0>(w), w1 = swz_head<1>(w);
        float w2 = swz_head<2>(w), w3 = swz_head<3>(w);
        float w4 = swz_head<4>(w), w5 = swz_head<5>(w);
        float w6 = swz_head<6>(w), w7 = swz_head<7>(w);
        uint4 hv = H4[(size_t)src * 32 + c];        // 16B gather: 8 bf16 head-vals
        acc[0] += w0 * bflo(hv.x);  acc[1] += w1 * bfhi(hv.x);
        acc[2] += w2 * bflo(hv.y);  acc[3] += w3 * bfhi(hv.y);
        acc[4] += w4 * bflo(hv.z);  acc[5] += w5 * bfhi(hv.z);
        acc[6] += w6 * bflo(hv.w);  acc[7] += w7 * bfhi(hv.w);
    }
    // collect the 8 per-head denominators (each owner lane has the full sum)
    float val = 0.f;
    val += acc[0] / swz_head<0>(wsum_own);
    val += acc[1] / swz_head<1>(wsum_own);
    val += acc[2] / swz_head<2>(wsum_own);
    val += acc[3] / swz_head<3>(wsum_own);
    val += acc[4] / swz_head<4>(wsum_own);
    val += acc[5] / swz_head<5>(wsum_own);
    val += acc[6] / swz_head<6>(wsum_own);
    val += acc[7] / swz_head<7>(wsum_own);
    val = val * 0.125f + b[c];
    out[t] = val > 0.f ? val : (__expf(val) - 1.f);
}

// ================= output head: 4 nodes/block (1 wave each), log_softmax
__global__ __launch_bounds__(256) void out_kernel(const float* __restrict__ hf,
        const float* __restrict__ Wo, const float* __restrict__ bo,
        float* __restrict__ out) {
    const int wave = threadIdx.x >> 6;
    const int lane = threadIdx.x & 63;
    const int n    = blockIdx.x * 4 + wave;
    __shared__ float hs[4][CH];
    if (n < N_NODES && lane < CH) hs[wave][lane] = hf[n * CH + lane];
    __syncthreads();
    if (n >= N_NODES) return;
    float logit = -INFINITY;
    if (lane < OUT_C) {
        float a = bo[lane];
        #pragma unroll
        for (int k = 0; k < CH; ++k) a += hs[wave][k] * Wo[k * OUT_C + lane];
        logit = a;
    }
    float m = logit;
    #pragma unroll
    for (int off = 32; off; off >>= 1) m = fmaxf(m, __shfl_xor(m, off, 64));
    float ex = (lane < OUT_C) ? __expf(logit - m) : 0.f;
    float ssum = ex;
    #pragma unroll
    for (int off = 32; off; off >>= 1) ssum += __shfl_xor(ssum, off, 64);
    if (lane < OUT_C) out[(size_t)n * OUT_C + lane] = logit - m - __logf(ssum);
}

extern "C" void kernel_launch(void* const* d_in, const int* in_sizes, int n_in,
                              void* d_out, int out_size, void* d_ws, size_t ws_size,
                              hipStream_t stream) {
    const float* x      = (const float*)d_in[0];
    const int*   ei     = (const int*)  d_in[1];
    const float* W1     = (const float*)d_in[2];
    const float* a_src1 = (const float*)d_in[3];
    const float* a_dst1 = (const float*)d_in[4];
    const float* b1     = (const float*)d_in[5];
    const float* W2     = (const float*)d_in[6];
    const float* a_src2 = (const float*)d_in[7];
    const float* a_dst2 = (const float*)d_in[8];
    const float* b2     = (const float*)d_in[9];
    const float* Wo     = (const float*)d_in[10];
    const float* bo     = (const float*)d_in[11];
    float* out = (float*)d_out;

    // workspace carve-up (256B-aligned)
    char* ws = (char*)d_ws;
    size_t off = 0;
    auto carve = [&](size_t bytes) { char* p = ws + off; off += (bytes + 255) & ~(size_t)255; return p; };
    u16*   ht      = (u16*)  carve((size_t)N_NODES * HC * 2);      // 25.6 MB (bf16, transposed)
    u16*   xb      = (u16*)  carve((size_t)N_PAD * F_IN * 2);      // 25.6 MB (bf16 x, padded rows)
    u16*   Wt      = (u16*)  carve((size_t)HC * F_IN * 2);         // 128 KB (bf16 W1^T)
    float* asrc    = (float*)carve((size_t)N_NODES * NHEAD * 4);   // 1.6 MB
    float* adst    = (float*)carve((size_t)N_NODES * NHEAD * 4);
    float* hmid    = (float*)carve((size_t)N_NODES * CH * 4);      // 6.4 MB
    float* hout    = (float*)carve((size_t)N_NODES * CH * 4);      // 6.4 MB
    int*   deg     = (int*)  carve((size_t)N_NODES * 4);
    int*   rowptr  = (int*)  carve((size_t)(N_NODES + 1) * 4);
    int*   cursor  = (int*)  carve((size_t)N_NODES * 4);
    int*   csr_src = (int*)  carve((size_t)E_TOT * 4);             // 3.4 MB
    int*   partials= (int*)  carve((size_t)SCAN_BLOCKS * 4);

    const int g_xcvt  = (N_NODES * F_IN / 8 + 255) / 256;    // 6250
    const int g_wcvt  = (HC * F_IN + 255) / 256;             // 256
    const int g_gemm1 = (N_NODES + 31) / 32;                 // 1563
    const int g_gemm2 = (N_NODES + G2_ROWS - 1) / G2_ROWS;   // 391
    const int g_nh    = (N_NODES * NHEAD + 255) / 256;       // 1563
    const int g_edge  = (E_TOT + 255) / 256;                 // 3321
    const int g_attn  = (N_NODES * CH + 255) / 256;          // 6250
    const int g_out   = (N_NODES + 3) / 4;                   // 12500

    // ---------- prep + CSR build ----------
    xcvt_kernel<<<g_xcvt, 256, 0, stream>>>(x, xb);
    wcvt_kernel<<<g_wcvt, 256, 0, stream>>>(W1, Wt);
    (void)hipMemsetAsync(deg, 0, (size_t)N_NODES * 4, stream);
    deg_kernel<<<g_edge, 256, 0, stream>>>(ei, deg);
    scan1_kernel<<<SCAN_BLOCKS, 256, 0, stream>>>(deg, rowptr, partials);
    scan2_kernel<<<1, 256, 0, stream>>>(partials);
    scan3_kernel<<<SCAN_BLOCKS, 256, 0, stream>>>(rowptr, cursor, partials);
    scatter_kernel<<<g_edge, 256, 0, stream>>>(ei, cursor, csr_src);

    // ---------- layer 1 ----------
    gemm1_mfma<<<g_gemm1, 256, 0, stream>>>(xb, Wt, ht);
    alpha_t_kernel<<<g_nh, 256, 0, stream>>>(ht, a_src1, a_dst1, asrc, adst);
    attn_kernel<<<g_attn, 256, 0, stream>>>(rowptr, csr_src, asrc, adst, ht, b1, hmid);

    // ---------- layer 2 ----------
    gemm2_kernel<<<g_gemm2, 256, 0, stream>>>(hmid, W2, ht, a_src2, a_dst2, asrc, adst);
    attn_kernel<<<g_attn, 256, 0, stream>>>(rowptr, csr_src, asrc, adst, ht, b2, hout);

    // ---------- output head ----------
    out_kernel<<<g_out, 256, 0, stream>>>(hout, Wo, bo, out);
}

// Round 13
// 492.205 us; speedup vs baseline: 3.9607x; 1.0800x over previous
//
#include <hip/hip_runtime.h>
#include <math.h>

#define N_NODES 50000
#define N_PAD   50016                 // padded to 32-row gemm tiles
#define N_EDGES 800000
#define E_TOT   (N_EDGES + N_NODES)   // edges + self-loops = 850000
#define F_IN    256
#define NHEAD   8
#define CH      32
#define HC      256                   // NHEAD*CH
#define OUT_C   40
#define NEG_SLOPE 0.2f
#define SCAN_BLOCKS ((N_NODES + 255) / 256)   // 196

typedef unsigned short u16;
typedef unsigned int   u32;
typedef __attribute__((ext_vector_type(8))) short bf16x8;   // 4 VGPRs
typedef __attribute__((ext_vector_type(4))) float f32x4;

__device__ __forceinline__ u16 f2bf(float f) {
    union { u32 u; float f; } x; x.f = f;
    u32 u = x.u;
    return (u16)((u + 0x7fffu + ((u >> 16) & 1u)) >> 16);   // round-nearest-even
}
__device__ __forceinline__ float bflo(u32 v) {
    union { u32 u; float f; } x; x.u = v << 16; return x.f;
}
__device__ __forceinline__ float bfhi(u32 v) {
    union { u32 u; float f; } x; x.u = v & 0xffff0000u; return x.f;
}
// broadcast-from-head-owner within each 8-lane group (BitMode: and=0x18, or=H)
template <int H>
__device__ __forceinline__ float swz_head(float v) {
    return __int_as_float(__builtin_amdgcn_ds_swizzle(__float_as_int(v),
                                                      (H << 5) | 0x18));
}

// ht is bf16, TRANSPOSED per node: ht[node*256 + c*8 + hd] -> the 8 head-values
// of channel c are 16 contiguous bytes (one uint4 gather in attn_kernel).

// ================= prep: x -> bf16 (row layout unchanged)
__global__ __launch_bounds__(256) void xcvt_kernel(const float* __restrict__ x,
        u16* __restrict__ xb) {
    int t = blockIdx.x * 256 + threadIdx.x;          // one per 8 elements
    if (t >= N_NODES * F_IN / 8) return;
    const float4* xp = (const float4*)x + (size_t)t * 2;
    float4 v0 = xp[0], v1 = xp[1];
    uint4 o;
    o.x = (u32)f2bf(v0.x) | ((u32)f2bf(v0.y) << 16);
    o.y = (u32)f2bf(v0.z) | ((u32)f2bf(v0.w) << 16);
    o.z = (u32)f2bf(v1.x) | ((u32)f2bf(v1.y) << 16);
    o.w = (u32)f2bf(v1.z) | ((u32)f2bf(v1.w) << 16);
    ((uint4*)xb)[t] = o;
}

// ================= prep: Wt[n][k] = bf16(W1[k][n])  (transpose for B-frags)
__global__ __launch_bounds__(256) void wcvt_kernel(const float* __restrict__ W,
        u16* __restrict__ Wt) {
    int t = blockIdx.x * 256 + threadIdx.x;          // 65536 total
    int n = t & 255, k = t >> 8;                     // coalesced reads
    Wt[(size_t)n * F_IN + k] = f2bf(W[(size_t)k * HC + n]);
}

// ================= prep: W2t[n][k] = bf16(W2[k][n]), k<32
__global__ __launch_bounds__(256) void wcvt2_kernel(const float* __restrict__ W,
        u16* __restrict__ W2t) {
    int t = blockIdx.x * 256 + threadIdx.x;          // 8192 total
    if (t >= HC * CH) return;
    int n = t & 255, k = t >> 8;                     // coalesced reads
    W2t[(size_t)n * CH + k] = f2bf(W[(size_t)k * HC + n]);
}

// ================= GEMM1 via MFMA bf16: ht = bf16(x @ W1), transposed store
// Frags (verified): A[m=lane&15][k=quad*8+j]; B from Wt[n][k]; C/D col=lane&15,
// row=quad*4+reg. No LDS; frag loads are 16B global (L1/L2-resident).
__global__ __launch_bounds__(256) void gemm1_mfma(const u16* __restrict__ xb,
        const u16* __restrict__ Wt, u16* __restrict__ ht) {
    const int row0 = blockIdx.x * 32;
    const int t    = threadIdx.x;
    const int wave = t >> 6;
    const int lane = t & 63;
    const int l16  = lane & 15;
    const int quad = lane >> 4;
    const int nb   = wave * 64;

    f32x4 acc[2][4];
    #pragma unroll
    for (int m = 0; m < 2; ++m)
        #pragma unroll
        for (int n = 0; n < 4; ++n) acc[m][n] = (f32x4){0.f, 0.f, 0.f, 0.f};

    const u16* a0p = xb + (size_t)(row0 + l16) * F_IN;        // M-tile 0
    const u16* a1p = a0p + 16 * F_IN;                         // M-tile 1
    const u16* bp  = Wt + (size_t)(nb + l16) * F_IN;          // N-tile stride 16*F_IN

    #pragma unroll 1
    for (int k0 = 0; k0 < F_IN; k0 += 32) {
        const int ko = k0 + quad * 8;
        bf16x8 a0 = *(const bf16x8*)(a0p + ko);
        bf16x8 a1 = *(const bf16x8*)(a1p + ko);
        bf16x8 b0 = *(const bf16x8*)(bp + 0 * 16 * F_IN + ko);
        bf16x8 b1 = *(const bf16x8*)(bp + 1 * 16 * F_IN + ko);
        bf16x8 b2 = *(const bf16x8*)(bp + 2 * 16 * F_IN + ko);
        bf16x8 b3 = *(const bf16x8*)(bp + 3 * 16 * F_IN + ko);
        acc[0][0] = __builtin_amdgcn_mfma_f32_16x16x32_bf16(a0, b0, acc[0][0], 0, 0, 0);
        acc[0][1] = __builtin_amdgcn_mfma_f32_16x16x32_bf16(a0, b1, acc[0][1], 0, 0, 0);
        acc[0][2] = __builtin_amdgcn_mfma_f32_16x16x32_bf16(a0, b2, acc[0][2], 0, 0, 0);
        acc[0][3] = __builtin_amdgcn_mfma_f32_16x16x32_bf16(a0, b3, acc[0][3], 0, 0, 0);
        acc[1][0] = __builtin_amdgcn_mfma_f32_16x16x32_bf16(a1, b0, acc[1][0], 0, 0, 0);
        acc[1][1] = __builtin_amdgcn_mfma_f32_16x16x32_bf16(a1, b1, acc[1][1], 0, 0, 0);
        acc[1][2] = __builtin_amdgcn_mfma_f32_16x16x32_bf16(a1, b2, acc[1][2], 0, 0, 0);
        acc[1][3] = __builtin_amdgcn_mfma_f32_16x16x32_bf16(a1, b3, acc[1][3], 0, 0, 0);
    }

    #pragma unroll
    for (int m = 0; m < 2; ++m) {
        #pragma unroll
        for (int r = 0; r < 4; ++r) {
            int row = row0 + m * 16 + quad * 4 + r;
            if (row < N_NODES) {
                u16* hr = ht + (size_t)row * HC;
                #pragma unroll
                for (int n = 0; n < 4; ++n) {
                    int col = nb + n * 16 + l16;
                    int hd = col >> 5, cc = col & 31;
                    hr[cc * 8 + hd] = f2bf(acc[m][n][r]);
                }
            }
        }
    }
}

// ================= GEMM2 via MFMA bf16: ht = bf16(hmb @ W2), K=32 single step
// (r12 post-mortem: vector gemm2 was 89us — 391 blocks, 15% occupancy, serial
// row loop + 10 shfl/row. Same structure as gemm1_mfma, 1563 blocks.)
__global__ __launch_bounds__(256) void gemm2_mfma(const u16* __restrict__ hmb,
        const u16* __restrict__ W2t, u16* __restrict__ ht) {
    const int row0 = blockIdx.x * 32;
    const int t    = threadIdx.x;
    const int wave = t >> 6;
    const int lane = t & 63;
    const int l16  = lane & 15;
    const int quad = lane >> 4;
    const int nb   = wave * 64;
    const int ko   = quad * 8;

    const u16* a0p = hmb + (size_t)(row0 + l16) * CH;
    const u16* a1p = a0p + 16 * CH;
    const u16* bp  = W2t + (size_t)(nb + l16) * CH;

    bf16x8 a0 = *(const bf16x8*)(a0p + ko);
    bf16x8 a1 = *(const bf16x8*)(a1p + ko);
    bf16x8 b0 = *(const bf16x8*)(bp + 0 * 16 * CH + ko);
    bf16x8 b1 = *(const bf16x8*)(bp + 1 * 16 * CH + ko);
    bf16x8 b2 = *(const bf16x8*)(bp + 2 * 16 * CH + ko);
    bf16x8 b3 = *(const bf16x8*)(bp + 3 * 16 * CH + ko);

    f32x4 z = (f32x4){0.f, 0.f, 0.f, 0.f};
    f32x4 acc[2][4];
    acc[0][0] = __builtin_amdgcn_mfma_f32_16x16x32_bf16(a0, b0, z, 0, 0, 0);
    acc[0][1] = __builtin_amdgcn_mfma_f32_16x16x32_bf16(a0, b1, z, 0, 0, 0);
    acc[0][2] = __builtin_amdgcn_mfma_f32_16x16x32_bf16(a0, b2, z, 0, 0, 0);
    acc[0][3] = __builtin_amdgcn_mfma_f32_16x16x32_bf16(a0, b3, z, 0, 0, 0);
    acc[1][0] = __builtin_amdgcn_mfma_f32_16x16x32_bf16(a1, b0, z, 0, 0, 0);
    acc[1][1] = __builtin_amdgcn_mfma_f32_16x16x32_bf16(a1, b1, z, 0, 0, 0);
    acc[1][2] = __builtin_amdgcn_mfma_f32_16x16x32_bf16(a1, b2, z, 0, 0, 0);
    acc[1][3] = __builtin_amdgcn_mfma_f32_16x16x32_bf16(a1, b3, z, 0, 0, 0);

    #pragma unroll
    for (int m = 0; m < 2; ++m) {
        #pragma unroll
        for (int r = 0; r < 4; ++r) {
            int row = row0 + m * 16 + quad * 4 + r;
            if (row < N_NODES) {
                u16* hr = ht + (size_t)row * HC;
                #pragma unroll
                for (int n = 0; n < 4; ++n) {
                    int col = nb + n * 16 + l16;
                    int hd = col >> 5, cc = col & 31;
                    hr[cc * 8 + hd] = f2bf(acc[m][n][r]);
                }
            }
        }
    }
}

// ================= alpha from transposed bf16 ht: asrc/adst [N,8]
__global__ __launch_bounds__(256) void alpha_t_kernel(const u16* __restrict__ ht,
        const float* __restrict__ a_src, const float* __restrict__ a_dst,
        float* __restrict__ asrc, float* __restrict__ adst) {
    int t = blockIdx.x * 256 + threadIdx.x;
    if (t >= N_NODES * NHEAD) return;
    int node = t >> 3;
    int hd   = t & 7;
    const u16* hp = ht + (size_t)node * HC + hd;
    const float* ap = a_src + hd * CH;
    const float* dp = a_dst + hd * CH;
    float s1 = 0.f, s2 = 0.f;
    #pragma unroll
    for (int c = 0; c < CH; ++c) {
        float hv = bflo((u32)hp[c * 8]);
        s1 += hv * ap[c];
        s2 += hv * dp[c];
    }
    asrc[t] = s1;
    adst[t] = s2;
}

// ================= CSR build =================
__global__ __launch_bounds__(256) void deg_kernel(const int* __restrict__ ei,
        int* __restrict__ deg) {
    int j = blockIdx.x * 256 + threadIdx.x;
    if (j >= E_TOT) return;
    int dst = (j < N_EDGES) ? ei[N_EDGES + j] : (j - N_EDGES);
    atomicAdd(&deg[dst], 1);
}

// -------- parallel 3-phase exclusive scan of deg -> rowptr/cursor
__device__ __forceinline__ int wave_incl_scan(int v, int lane) {
    #pragma unroll
    for (int d = 1; d < 64; d <<= 1) {
        int u = __shfl_up(v, d, 64);
        if (lane >= d) v += u;
    }
    return v;
}

__global__ __launch_bounds__(256) void scan1_kernel(const int* __restrict__ deg,
        int* __restrict__ rowptr, int* __restrict__ partials) {
    const int t    = blockIdx.x * 256 + threadIdx.x;
    const int lane = threadIdx.x & 63;
    const int wid  = threadIdx.x >> 6;
    int v = (t < N_NODES) ? deg[t] : 0;
    int inc = wave_incl_scan(v, lane);
    __shared__ int wtot[4];
    if (lane == 63) wtot[wid] = inc;
    __syncthreads();
    int woff = 0;
    #pragma unroll
    for (int i = 0; i < 4; ++i) woff += (i < wid) ? wtot[i] : 0;
    if (t < N_NODES) rowptr[t] = inc - v + woff;      // block-local exclusive
    if (threadIdx.x == 255) partials[blockIdx.x] = woff + inc;  // block total
}

__global__ __launch_bounds__(256) void scan2_kernel(int* __restrict__ partials) {
    const int t    = threadIdx.x;
    const int lane = t & 63;
    const int wid  = t >> 6;
    int v = (t < SCAN_BLOCKS) ? partials[t] : 0;
    int inc = wave_incl_scan(v, lane);
    __shared__ int wtot[4];
    if (lane == 63) wtot[wid] = inc;
    __syncthreads();
    int woff = 0;
    #pragma unroll
    for (int i = 0; i < 4; ++i) woff += (i < wid) ? wtot[i] : 0;
    __syncthreads();
    if (t < SCAN_BLOCKS) partials[t] = inc - v + woff;
}

__global__ __launch_bounds__(256) void scan3_kernel(int* __restrict__ rowptr,
        int* __restrict__ cursor, const int* __restrict__ partials) {
    const int t = blockIdx.x * 256 + threadIdx.x;
    if (t < N_NODES) {
        int v = rowptr[t] + partials[blockIdx.x];
        rowptr[t] = v;
        cursor[t] = v;
    } else if (t == N_NODES) {
        rowptr[N_NODES] = E_TOT;
    }
}

__global__ __launch_bounds__(256) void scatter_kernel(const int* __restrict__ ei,
        int* __restrict__ cursor, int* __restrict__ csr_src) {
    int j = blockIdx.x * 256 + threadIdx.x;
    if (j >= E_TOT) return;
    int src, dst;
    if (j < N_EDGES) { src = ei[j]; dst = ei[N_EDGES + j]; }
    else             { src = j - N_EDGES; dst = src; }
    int pos = atomicAdd(&cursor[dst], 1);
    csr_src[pos] = src;
}

// ================= fused attention: softmax + aggregate in ONE pass
// Lane l computes only head (l&7)'s exp; 8 ds_swizzles distribute w0..w7.
// Output is bf16 (feeds gemm2_mfma / out_kernel).
__global__ __launch_bounds__(256) void attn_kernel(const int* __restrict__ rowptr,
        const int* __restrict__ csr_src, const float* __restrict__ asrc,
        const float* __restrict__ adst, const u16* __restrict__ ht,
        const float* __restrict__ b, u16* __restrict__ out) {
    int t = blockIdx.x * 256 + threadIdx.x;
    if (t >= N_NODES * CH) return;
    int dst = t >> 5;
    int c   = t & 31;
    int hown = c & 7;                               // this lane's owned head
    const float ad_own = adst[dst * NHEAD + hown];
    const uint4* H4 = (const uint4*)ht;   // row = 32 uint4; lane c reads uint4 #c

    float acc[NHEAD];
    #pragma unroll
    for (int h = 0; h < NHEAD; ++h) acc[h] = 0.f;
    float wsum_own = 0.f;

    int p0 = rowptr[dst], p1 = rowptr[dst + 1];
    for (int p = p0; p < p1; ++p) {
        int src = csr_src[p];                       // broadcast across 32 lanes
        float e = asrc[src * NHEAD + hown] + ad_own;   // own head only
        e = e > 0.f ? e : NEG_SLOPE * e;
        float w = __expf(e);                        // ONE exp per lane
        wsum_own += w;
        float w0 = swz_head<0>(w), w1 = swz_head<1>(w);
        float w2 = swz_head<2>(w), w3 = swz_head<3>(w);
        float w4 = swz_head<4>(w), w5 = swz_head<5>(w);
        float w6 = swz_head<6>(w), w7 = swz_head<7>(w);
        uint4 hv = H4[(size_t)src * 32 + c];        // 16B gather: 8 bf16 head-vals
        acc[0] += w0 * bflo(hv.x);  acc[1] += w1 * bfhi(hv.x);
        acc[2] += w2 * bflo(hv.y);  acc[3] += w3 * bfhi(hv.y);
        acc[4] += w4 * bflo(hv.z);  acc[5] += w5 * bfhi(hv.z);
        acc[6] += w6 * bflo(hv.w);  acc[7] += w7 * bfhi(hv.w);
    }
    float val = 0.f;
    val += acc[0] / swz_head<0>(wsum_own);
    val += acc[1] / swz_head<1>(wsum_own);
    val += acc[2] / swz_head<2>(wsum_own);
    val += acc[3] / swz_head<3>(wsum_own);
    val += acc[4] / swz_head<4>(wsum_own);
    val += acc[5] / swz_head<5>(wsum_own);
    val += acc[6] / swz_head<6>(wsum_own);
    val += acc[7] / swz_head<7>(wsum_own);
    val = val * 0.125f + b[c];
    val = val > 0.f ? val : (__expf(val) - 1.f);
    out[t] = f2bf(val);
}

// ================= output head: 4 nodes/block (1 wave each), log_softmax
__global__ __launch_bounds__(256) void out_kernel(const u16* __restrict__ hf,
        const float* __restrict__ Wo, const float* __restrict__ bo,
        float* __restrict__ out) {
    const int wave = threadIdx.x >> 6;
    const int lane = threadIdx.x & 63;
    const int n    = blockIdx.x * 4 + wave;
    __shared__ float hs[4][CH];
    if (n < N_NODES && lane < CH) hs[wave][lane] = bflo((u32)hf[n * CH + lane]);
    __syncthreads();
    if (n >= N_NODES) return;
    float logit = -INFINITY;
    if (lane < OUT_C) {
        float a = bo[lane];
        #pragma unroll
        for (int k = 0; k < CH; ++k) a += hs[wave][k] * Wo[k * OUT_C + lane];
        logit = a;
    }
    float m = logit;
    #pragma unroll
    for (int off = 32; off; off >>= 1) m = fmaxf(m, __shfl_xor(m, off, 64));
    float ex = (lane < OUT_C) ? __expf(logit - m) : 0.f;
    float ssum = ex;
    #pragma unroll
    for (int off = 32; off; off >>= 1) ssum += __shfl_xor(ssum, off, 64);
    if (lane < OUT_C) out[(size_t)n * OUT_C + lane] = logit - m - __logf(ssum);
}

extern "C" void kernel_launch(void* const* d_in, const int* in_sizes, int n_in,
                              void* d_out, int out_size, void* d_ws, size_t ws_size,
                              hipStream_t stream) {
    const float* x      = (const float*)d_in[0];
    const int*   ei     = (const int*)  d_in[1];
    const float* W1     = (const float*)d_in[2];
    const float* a_src1 = (const float*)d_in[3];
    const float* a_dst1 = (const float*)d_in[4];
    const float* b1     = (const float*)d_in[5];
    const float* W2     = (const float*)d_in[6];
    const float* a_src2 = (const float*)d_in[7];
    const float* a_dst2 = (const float*)d_in[8];
    const float* b2     = (const float*)d_in[9];
    const float* Wo     = (const float*)d_in[10];
    const float* bo     = (const float*)d_in[11];
    float* out = (float*)d_out;

    // workspace carve-up (256B-aligned)
    char* ws = (char*)d_ws;
    size_t off = 0;
    auto carve = [&](size_t bytes) { char* p = ws + off; off += (bytes + 255) & ~(size_t)255; return p; };
    u16*   ht      = (u16*)  carve((size_t)N_NODES * HC * 2);      // 25.6 MB (bf16, transposed)
    u16*   xb      = (u16*)  carve((size_t)N_PAD * F_IN * 2);      // 25.6 MB (bf16 x, padded)
    u16*   Wt      = (u16*)  carve((size_t)HC * F_IN * 2);         // 128 KB (bf16 W1^T)
    u16*   W2t     = (u16*)  carve((size_t)HC * CH * 2);           // 16 KB (bf16 W2^T)
    float* asrc    = (float*)carve((size_t)N_NODES * NHEAD * 4);   // 1.6 MB
    float* adst    = (float*)carve((size_t)N_NODES * NHEAD * 4);
    u16*   hmid    = (u16*)  carve((size_t)N_PAD * CH * 2);        // 3.2 MB (bf16)
    u16*   hout    = (u16*)  carve((size_t)N_NODES * CH * 2);      // 3.2 MB (bf16)
    int*   deg     = (int*)  carve((size_t)N_NODES * 4);
    int*   rowptr  = (int*)  carve((size_t)(N_NODES + 1) * 4);
    int*   cursor  = (int*)  carve((size_t)N_NODES * 4);
    int*   csr_src = (int*)  carve((size_t)E_TOT * 4);             // 3.4 MB
    int*   partials= (int*)  carve((size_t)SCAN_BLOCKS * 4);

    const int g_xcvt  = (N_NODES * F_IN / 8 + 255) / 256;    // 6250
    const int g_wcvt  = (HC * F_IN + 255) / 256;             // 256
    const int g_wcvt2 = (HC * CH + 255) / 256;               // 32
    const int g_gemm  = (N_NODES + 31) / 32;                 // 1563
    const int g_nh    = (N_NODES * NHEAD + 255) / 256;       // 1563
    const int g_edge  = (E_TOT + 255) / 256;                 // 3321
    const int g_attn  = (N_NODES * CH + 255) / 256;          // 6250
    const int g_out   = (N_NODES + 3) / 4;                   // 12500

    // ---------- prep + CSR build ----------
    xcvt_kernel<<<g_xcvt, 256, 0, stream>>>(x, xb);
    wcvt_kernel<<<g_wcvt, 256, 0, stream>>>(W1, Wt);
    wcvt2_kernel<<<g_wcvt2, 256, 0, stream>>>(W2, W2t);
    (void)hipMemsetAsync(deg, 0, (size_t)N_NODES * 4, stream);
    deg_kernel<<<g_edge, 256, 0, stream>>>(ei, deg);
    scan1_kernel<<<SCAN_BLOCKS, 256, 0, stream>>>(deg, rowptr, partials);
    scan2_kernel<<<1, 256, 0, stream>>>(partials);
    scan3_kernel<<<SCAN_BLOCKS, 256, 0, stream>>>(rowptr, cursor, partials);
    scatter_kernel<<<g_edge, 256, 0, stream>>>(ei, cursor, csr_src);

    // ---------- layer 1 ----------
    gemm1_mfma<<<g_gemm, 256, 0, stream>>>(xb, Wt, ht);
    alpha_t_kernel<<<g_nh, 256, 0, stream>>>(ht, a_src1, a_dst1, asrc, adst);
    attn_kernel<<<g_attn, 256, 0, stream>>>(rowptr, csr_src, asrc, adst, ht, b1, hmid);

    // ---------- layer 2 ----------
    gemm2_mfma<<<g_gemm, 256, 0, stream>>>(hmid, W2t, ht);
    alpha_t_kernel<<<g_nh, 256, 0, stream>>>(ht, a_src2, a_dst2, asrc, adst);
    attn_kernel<<<g_attn, 256, 0, stream>>>(rowptr, csr_src, asrc, adst, ht, b2, hout);

    // ---------- output head ----------
    out_kernel<<<g_out, 256, 0, stream>>>(hout, Wo, bo, out);
}

// Round 14
// 477.212 us; speedup vs baseline: 4.0851x; 1.0314x over previous
//
#include <hip/hip_runtime.h>
#include <math.h>

#define N_NODES 50000
#define N_PAD   50016                 // padded to 32-row gemm tiles
#define N_EDGES 800000
#define E_TOT   (N_EDGES + N_NODES)   // edges + self-loops = 850000
#define F_IN    256
#define NHEAD   8
#define CH      32
#define HC      256                   // NHEAD*CH
#define OUT_C   40
#define NEG_SLOPE 0.2f
#define SCAN_BLOCKS ((N_NODES + 255) / 256)   // 196
#define G_XCVT  ((N_NODES * F_IN / 8 + 255) / 256)   // 6250
#define G_WCVT  ((HC * F_IN + 255) / 256)            // 256
#define G_WCVT2 ((HC * CH + 255) / 256)              // 32

typedef unsigned short u16;
typedef unsigned int   u32;
typedef __attribute__((ext_vector_type(8))) short bf16x8;   // 4 VGPRs
typedef __attribute__((ext_vector_type(4))) float f32x4;

__device__ __forceinline__ u16 f2bf(float f) {
    union { u32 u; float f; } x; x.f = f;
    u32 u = x.u;
    return (u16)((u + 0x7fffu + ((u >> 16) & 1u)) >> 16);   // round-nearest-even
}
__device__ __forceinline__ float bflo(u32 v) {
    union { u32 u; float f; } x; x.u = v << 16; return x.f;
}
__device__ __forceinline__ float bfhi(u32 v) {
    union { u32 u; float f; } x; x.u = v & 0xffff0000u; return x.f;
}
// broadcast-from-head-owner within each 8-lane group (BitMode: and=0x18, or=H)
template <int H>
__device__ __forceinline__ float swz_head(float v) {
    return __int_as_float(__builtin_amdgcn_ds_swizzle(__float_as_int(v),
                                                      (H << 5) | 0x18));
}

// ht is bf16, TRANSPOSED per node: ht[node*256 + c*8 + hd] -> the 8 head-values
// of channel c are 16 contiguous bytes (one uint4 gather in attn_kernel).

// ================= fused prep: x->bf16, W1->bf16^T, W2->bf16^T (one launch)
__global__ __launch_bounds__(256) void cvt_kernel(const float* __restrict__ x,
        u16* __restrict__ xb, const float* __restrict__ W1, u16* __restrict__ Wt,
        const float* __restrict__ W2, u16* __restrict__ W2t) {
    int b = blockIdx.x;
    if (b < G_XCVT) {
        int t = b * 256 + threadIdx.x;               // one per 8 elements
        if (t >= N_NODES * F_IN / 8) return;
        const float4* xp = (const float4*)x + (size_t)t * 2;
        float4 v0 = xp[0], v1 = xp[1];
        uint4 o;
        o.x = (u32)f2bf(v0.x) | ((u32)f2bf(v0.y) << 16);
        o.y = (u32)f2bf(v0.z) | ((u32)f2bf(v0.w) << 16);
        o.z = (u32)f2bf(v1.x) | ((u32)f2bf(v1.y) << 16);
        o.w = (u32)f2bf(v1.z) | ((u32)f2bf(v1.w) << 16);
        ((uint4*)xb)[t] = o;
    } else if (b < G_XCVT + G_WCVT) {
        int t = (b - G_XCVT) * 256 + threadIdx.x;    // 65536 total
        int n = t & 255, k = t >> 8;                 // coalesced reads
        Wt[(size_t)n * F_IN + k] = f2bf(W1[(size_t)k * HC + n]);
    } else {
        int t = (b - G_XCVT - G_WCVT) * 256 + threadIdx.x;  // 8192 total
        if (t >= HC * CH) return;
        int n = t & 255, k = t >> 8;
        W2t[(size_t)n * CH + k] = f2bf(W2[(size_t)k * HC + n]);
    }
}

// ================= GEMM1 via MFMA bf16: ht = bf16(x @ W1), transposed store
// Frags (verified): A[m=lane&15][k=quad*8+j]; B from Wt[n][k]; C/D col=lane&15,
// row=quad*4+reg. No LDS; frag loads are 16B global (L1/L2-resident).
__global__ __launch_bounds__(256) void gemm1_mfma(const u16* __restrict__ xb,
        const u16* __restrict__ Wt, u16* __restrict__ ht) {
    const int row0 = blockIdx.x * 32;
    const int t    = threadIdx.x;
    const int wave = t >> 6;
    const int lane = t & 63;
    const int l16  = lane & 15;
    const int quad = lane >> 4;
    const int nb   = wave * 64;

    f32x4 acc[2][4];
    #pragma unroll
    for (int m = 0; m < 2; ++m)
        #pragma unroll
        for (int n = 0; n < 4; ++n) acc[m][n] = (f32x4){0.f, 0.f, 0.f, 0.f};

    const u16* a0p = xb + (size_t)(row0 + l16) * F_IN;        // M-tile 0
    const u16* a1p = a0p + 16 * F_IN;                         // M-tile 1
    const u16* bp  = Wt + (size_t)(nb + l16) * F_IN;          // N-tile stride 16*F_IN

    #pragma unroll 1
    for (int k0 = 0; k0 < F_IN; k0 += 32) {
        const int ko = k0 + quad * 8;
        bf16x8 a0 = *(const bf16x8*)(a0p + ko);
        bf16x8 a1 = *(const bf16x8*)(a1p + ko);
        bf16x8 b0 = *(const bf16x8*)(bp + 0 * 16 * F_IN + ko);
        bf16x8 b1 = *(const bf16x8*)(bp + 1 * 16 * F_IN + ko);
        bf16x8 b2 = *(const bf16x8*)(bp + 2 * 16 * F_IN + ko);
        bf16x8 b3 = *(const bf16x8*)(bp + 3 * 16 * F_IN + ko);
        acc[0][0] = __builtin_amdgcn_mfma_f32_16x16x32_bf16(a0, b0, acc[0][0], 0, 0, 0);
        acc[0][1] = __builtin_amdgcn_mfma_f32_16x16x32_bf16(a0, b1, acc[0][1], 0, 0, 0);
        acc[0][2] = __builtin_amdgcn_mfma_f32_16x16x32_bf16(a0, b2, acc[0][2], 0, 0, 0);
        acc[0][3] = __builtin_amdgcn_mfma_f32_16x16x32_bf16(a0, b3, acc[0][3], 0, 0, 0);
        acc[1][0] = __builtin_amdgcn_mfma_f32_16x16x32_bf16(a1, b0, acc[1][0], 0, 0, 0);
        acc[1][1] = __builtin_amdgcn_mfma_f32_16x16x32_bf16(a1, b1, acc[1][1], 0, 0, 0);
        acc[1][2] = __builtin_amdgcn_mfma_f32_16x16x32_bf16(a1, b2, acc[1][2], 0, 0, 0);
        acc[1][3] = __builtin_amdgcn_mfma_f32_16x16x32_bf16(a1, b3, acc[1][3], 0, 0, 0);
    }

    #pragma unroll
    for (int m = 0; m < 2; ++m) {
        #pragma unroll
        for (int r = 0; r < 4; ++r) {
            int row = row0 + m * 16 + quad * 4 + r;
            if (row < N_NODES) {
                u16* hr = ht + (size_t)row * HC;
                #pragma unroll
                for (int n = 0; n < 4; ++n) {
                    int col = nb + n * 16 + l16;
                    int hd = col >> 5, cc = col & 31;
                    hr[cc * 8 + hd] = f2bf(acc[m][n][r]);
                }
            }
        }
    }
}

// ================= GEMM2 via MFMA bf16: ht = bf16(hmb @ W2), K=32 single step
__global__ __launch_bounds__(256) void gemm2_mfma(const u16* __restrict__ hmb,
        const u16* __restrict__ W2t, u16* __restrict__ ht) {
    const int row0 = blockIdx.x * 32;
    const int t    = threadIdx.x;
    const int wave = t >> 6;
    const int lane = t & 63;
    const int l16  = lane & 15;
    const int quad = lane >> 4;
    const int nb   = wave * 64;
    const int ko   = quad * 8;

    const u16* a0p = hmb + (size_t)(row0 + l16) * CH;
    const u16* a1p = a0p + 16 * CH;
    const u16* bp  = W2t + (size_t)(nb + l16) * CH;

    bf16x8 a0 = *(const bf16x8*)(a0p + ko);
    bf16x8 a1 = *(const bf16x8*)(a1p + ko);
    bf16x8 b0 = *(const bf16x8*)(bp + 0 * 16 * CH + ko);
    bf16x8 b1 = *(const bf16x8*)(bp + 1 * 16 * CH + ko);
    bf16x8 b2 = *(const bf16x8*)(bp + 2 * 16 * CH + ko);
    bf16x8 b3 = *(const bf16x8*)(bp + 3 * 16 * CH + ko);

    f32x4 z = (f32x4){0.f, 0.f, 0.f, 0.f};
    f32x4 acc[2][4];
    acc[0][0] = __builtin_amdgcn_mfma_f32_16x16x32_bf16(a0, b0, z, 0, 0, 0);
    acc[0][1] = __builtin_amdgcn_mfma_f32_16x16x32_bf16(a0, b1, z, 0, 0, 0);
    acc[0][2] = __builtin_amdgcn_mfma_f32_16x16x32_bf16(a0, b2, z, 0, 0, 0);
    acc[0][3] = __builtin_amdgcn_mfma_f32_16x16x32_bf16(a0, b3, z, 0, 0, 0);
    acc[1][0] = __builtin_amdgcn_mfma_f32_16x16x32_bf16(a1, b0, z, 0, 0, 0);
    acc[1][1] = __builtin_amdgcn_mfma_f32_16x16x32_bf16(a1, b1, z, 0, 0, 0);
    acc[1][2] = __builtin_amdgcn_mfma_f32_16x16x32_bf16(a1, b2, z, 0, 0, 0);
    acc[1][3] = __builtin_amdgcn_mfma_f32_16x16x32_bf16(a1, b3, z, 0, 0, 0);

    #pragma unroll
    for (int m = 0; m < 2; ++m) {
        #pragma unroll
        for (int r = 0; r < 4; ++r) {
            int row = row0 + m * 16 + quad * 4 + r;
            if (row < N_NODES) {
                u16* hr = ht + (size_t)row * HC;
                #pragma unroll
                for (int n = 0; n < 4; ++n) {
                    int col = nb + n * 16 + l16;
                    int hd = col >> 5, cc = col & 31;
                    hr[cc * 8 + hd] = f2bf(acc[m][n][r]);
                }
            }
        }
    }
}

// ================= alpha from transposed bf16 ht: asrc/adst [N,8]
__global__ __launch_bounds__(256) void alpha_t_kernel(const u16* __restrict__ ht,
        const float* __restrict__ a_src, const float* __restrict__ a_dst,
        float* __restrict__ asrc, float* __restrict__ adst) {
    int t = blockIdx.x * 256 + threadIdx.x;
    if (t >= N_NODES * NHEAD) return;
    int node = t >> 3;
    int hd   = t & 7;
    const u16* hp = ht + (size_t)node * HC + hd;
    const float* ap = a_src + hd * CH;
    const float* dp = a_dst + hd * CH;
    float s1 = 0.f, s2 = 0.f;
    #pragma unroll
    for (int c = 0; c < CH; ++c) {
        float hv = bflo((u32)hp[c * 8]);
        s1 += hv * ap[c];
        s2 += hv * dp[c];
    }
    asrc[t] = s1;
    adst[t] = s2;
}

// ================= CSR build =================
__global__ __launch_bounds__(256) void deg_kernel(const int* __restrict__ ei,
        int* __restrict__ deg) {
    int j = blockIdx.x * 256 + threadIdx.x;
    if (j >= E_TOT) return;
    int dst = (j < N_EDGES) ? ei[N_EDGES + j] : (j - N_EDGES);
    atomicAdd(&deg[dst], 1);
}

__device__ __forceinline__ int wave_incl_scan(int v, int lane) {
    #pragma unroll
    for (int d = 1; d < 64; d <<= 1) {
        int u = __shfl_up(v, d, 64);
        if (lane >= d) v += u;
    }
    return v;
}

__global__ __launch_bounds__(256) void scan1_kernel(const int* __restrict__ deg,
        int* __restrict__ rowptr, int* __restrict__ partials) {
    const int t    = blockIdx.x * 256 + threadIdx.x;
    const int lane = threadIdx.x & 63;
    const int wid  = threadIdx.x >> 6;
    int v = (t < N_NODES) ? deg[t] : 0;
    int inc = wave_incl_scan(v, lane);
    __shared__ int wtot[4];
    if (lane == 63) wtot[wid] = inc;
    __syncthreads();
    int woff = 0;
    #pragma unroll
    for (int i = 0; i < 4; ++i) woff += (i < wid) ? wtot[i] : 0;
    if (t < N_NODES) rowptr[t] = inc - v + woff;      // block-local exclusive
    if (threadIdx.x == 255) partials[blockIdx.x] = woff + inc;  // block total
}

__global__ __launch_bounds__(256) void scan2_kernel(int* __restrict__ partials) {
    const int t    = threadIdx.x;
    const int lane = t & 63;
    const int wid  = t >> 6;
    int v = (t < SCAN_BLOCKS) ? partials[t] : 0;
    int inc = wave_incl_scan(v, lane);
    __shared__ int wtot[4];
    if (lane == 63) wtot[wid] = inc;
    __syncthreads();
    int woff = 0;
    #pragma unroll
    for (int i = 0; i < 4; ++i) woff += (i < wid) ? wtot[i] : 0;
    __syncthreads();
    if (t < SCAN_BLOCKS) partials[t] = inc - v + woff;
}

__global__ __launch_bounds__(256) void scan3_kernel(int* __restrict__ rowptr,
        int* __restrict__ cursor, const int* __restrict__ partials) {
    const int t = blockIdx.x * 256 + threadIdx.x;
    if (t < N_NODES) {
        int v = rowptr[t] + partials[blockIdx.x];
        rowptr[t] = v;
        cursor[t] = v;
    } else if (t == N_NODES) {
        rowptr[N_NODES] = E_TOT;
    }
}

__global__ __launch_bounds__(256) void scatter_kernel(const int* __restrict__ ei,
        int* __restrict__ cursor, int* __restrict__ csr_src) {
    int j = blockIdx.x * 256 + threadIdx.x;
    if (j >= E_TOT) return;
    int src, dst;
    if (j < N_EDGES) { src = ei[j]; dst = ei[N_EDGES + j]; }
    else             { src = j - N_EDGES; dst = src; }
    int pos = atomicAdd(&cursor[dst], 1);
    csr_src[pos] = src;
}

// ================= fused attention: softmax + aggregate in ONE pass
// r13 post-mortem: 80us, VALUBusy 34% (issue-bound would be ~100%) — stalled on
// the serial csr->gather chain. Fix: depth-1 software pipeline — prefetch
// csr_src/asrc/ht for edge p+1 before computing edge p.
__global__ __launch_bounds__(256) void attn_kernel(const int* __restrict__ rowptr,
        const int* __restrict__ csr_src, const float* __restrict__ asrc,
        const float* __restrict__ adst, const u16* __restrict__ ht,
        const float* __restrict__ b, u16* __restrict__ out) {
    int t = blockIdx.x * 256 + threadIdx.x;
    if (t >= N_NODES * CH) return;
    int dst = t >> 5;
    int c   = t & 31;
    int hown = c & 7;                               // this lane's owned head
    const float ad_own = adst[dst * NHEAD + hown];
    const uint4* H4 = (const uint4*)ht;   // row = 32 uint4; lane c reads uint4 #c

    float acc[NHEAD];
    #pragma unroll
    for (int h = 0; h < NHEAD; ++h) acc[h] = 0.f;
    float wsum_own = 0.f;

    int p0 = rowptr[dst], p1 = rowptr[dst + 1];
    // prologue: every dst has >=1 edge (self-loop)
    int   src0 = csr_src[p0];
    float as_n = asrc[src0 * NHEAD + hown];
    uint4 hv_n = H4[(size_t)src0 * 32 + c];
    for (int p = p0; p < p1; ++p) {
        float as_c = as_n;
        uint4 hv_c = hv_n;
        int pn = p + 1;
        if (pn < p1) {                              // prefetch next edge
            int srcn = csr_src[pn];
            as_n = asrc[srcn * NHEAD + hown];
            hv_n = H4[(size_t)srcn * 32 + c];
        }
        float e = as_c + ad_own;
        e = e > 0.f ? e : NEG_SLOPE * e;
        float w = __expf(e);                        // ONE exp per lane
        wsum_own += w;
        float w0 = swz_head<0>(w), w1 = swz_head<1>(w);
        float w2 = swz_head<2>(w), w3 = swz_head<3>(w);
        float w4 = swz_head<4>(w), w5 = swz_head<5>(w);
        float w6 = swz_head<6>(w), w7 = swz_head<7>(w);
        acc[0] += w0 * bflo(hv_c.x);  acc[1] += w1 * bfhi(hv_c.x);
        acc[2] += w2 * bflo(hv_c.y);  acc[3] += w3 * bfhi(hv_c.y);
        acc[4] += w4 * bflo(hv_c.z);  acc[5] += w5 * bfhi(hv_c.z);
        acc[6] += w6 * bflo(hv_c.w);  acc[7] += w7 * bfhi(hv_c.w);
    }
    float val = 0.f;
    val += acc[0] / swz_head<0>(wsum_own);
    val += acc[1] / swz_head<1>(wsum_own);
    val += acc[2] / swz_head<2>(wsum_own);
    val += acc[3] / swz_head<3>(wsum_own);
    val += acc[4] / swz_head<4>(wsum_own);
    val += acc[5] / swz_head<5>(wsum_own);
    val += acc[6] / swz_head<6>(wsum_own);
    val += acc[7] / swz_head<7>(wsum_own);
    val = val * 0.125f + b[c];
    val = val > 0.f ? val : (__expf(val) - 1.f);
    out[t] = f2bf(val);
}

// ================= output head: 4 nodes/block (1 wave each), log_softmax
__global__ __launch_bounds__(256) void out_kernel(const u16* __restrict__ hf,
        const float* __restrict__ Wo, const float* __restrict__ bo,
        float* __restrict__ out) {
    const int wave = threadIdx.x >> 6;
    const int lane = threadIdx.x & 63;
    const int n    = blockIdx.x * 4 + wave;
    __shared__ float hs[4][CH];
    if (n < N_NODES && lane < CH) hs[wave][lane] = bflo((u32)hf[n * CH + lane]);
    __syncthreads();
    if (n >= N_NODES) return;
    float logit = -INFINITY;
    if (lane < OUT_C) {
        float a = bo[lane];
        #pragma unroll
        for (int k = 0; k < CH; ++k) a += hs[wave][k] * Wo[k * OUT_C + lane];
        logit = a;
    }
    float m = logit;
    #pragma unroll
    for (int off = 32; off; off >>= 1) m = fmaxf(m, __shfl_xor(m, off, 64));
    float ex = (lane < OUT_C) ? __expf(logit - m) : 0.f;
    float ssum = ex;
    #pragma unroll
    for (int off = 32; off; off >>= 1) ssum += __shfl_xor(ssum, off, 64);
    if (lane < OUT_C) out[(size_t)n * OUT_C + lane] = logit - m - __logf(ssum);
}

extern "C" void kernel_launch(void* const* d_in, const int* in_sizes, int n_in,
                              void* d_out, int out_size, void* d_ws, size_t ws_size,
                              hipStream_t stream) {
    const float* x      = (const float*)d_in[0];
    const int*   ei     = (const int*)  d_in[1];
    const float* W1     = (const float*)d_in[2];
    const float* a_src1 = (const float*)d_in[3];
    const float* a_dst1 = (const float*)d_in[4];
    const float* b1     = (const float*)d_in[5];
    const float* W2     = (const float*)d_in[6];
    const float* a_src2 = (const float*)d_in[7];
    const float* a_dst2 = (const float*)d_in[8];
    const float* b2     = (const float*)d_in[9];
    const float* Wo     = (const float*)d_in[10];
    const float* bo     = (const float*)d_in[11];
    float* out = (float*)d_out;

    // workspace carve-up (256B-aligned)
    char* ws = (char*)d_ws;
    size_t off = 0;
    auto carve = [&](size_t bytes) { char* p = ws + off; off += (bytes + 255) & ~(size_t)255; return p; };
    u16*   ht      = (u16*)  carve((size_t)N_NODES * HC * 2);      // 25.6 MB (bf16, transposed)
    u16*   xb      = (u16*)  carve((size_t)N_PAD * F_IN * 2);      // 25.6 MB (bf16 x, padded)
    u16*   Wt      = (u16*)  carve((size_t)HC * F_IN * 2);         // 128 KB (bf16 W1^T)
    u16*   W2t     = (u16*)  carve((size_t)HC * CH * 2);           // 16 KB (bf16 W2^T)
    float* asrc    = (float*)carve((size_t)N_NODES * NHEAD * 4);   // 1.6 MB
    float* adst    = (float*)carve((size_t)N_NODES * NHEAD * 4);
    u16*   hmid    = (u16*)  carve((size_t)N_PAD * CH * 2);        // 3.2 MB (bf16)
    u16*   hout    = (u16*)  carve((size_t)N_NODES * CH * 2);      // 3.2 MB (bf16)
    int*   deg     = (int*)  carve((size_t)N_NODES * 4);
    int*   rowptr  = (int*)  carve((size_t)(N_NODES + 1) * 4);
    int*   cursor  = (int*)  carve((size_t)N_NODES * 4);
    int*   csr_src = (int*)  carve((size_t)E_TOT * 4);             // 3.4 MB
    int*   partials= (int*)  carve((size_t)SCAN_BLOCKS * 4);

    const int g_cvt   = G_XCVT + G_WCVT + G_WCVT2;           // 6538
    const int g_gemm  = (N_NODES + 31) / 32;                 // 1563
    const int g_nh    = (N_NODES * NHEAD + 255) / 256;       // 1563
    const int g_edge  = (E_TOT + 255) / 256;                 // 3321
    const int g_attn  = (N_NODES * CH + 255) / 256;          // 6250
    const int g_out   = (N_NODES + 3) / 4;                   // 12500

    // ---------- prep + CSR build ----------
    cvt_kernel<<<g_cvt, 256, 0, stream>>>(x, xb, W1, Wt, W2, W2t);
    (void)hipMemsetAsync(deg, 0, (size_t)N_NODES * 4, stream);
    deg_kernel<<<g_edge, 256, 0, stream>>>(ei, deg);
    scan1_kernel<<<SCAN_BLOCKS, 256, 0, stream>>>(deg, rowptr, partials);
    scan2_kernel<<<1, 256, 0, stream>>>(partials);
    scan3_kernel<<<SCAN_BLOCKS, 256, 0, stream>>>(rowptr, cursor, partials);
    scatter_kernel<<<g_edge, 256, 0, stream>>>(ei, cursor, csr_src);

    // ---------- layer 1 ----------
    gemm1_mfma<<<g_gemm, 256, 0, stream>>>(xb, Wt, ht);
    alpha_t_kernel<<<g_nh, 256, 0, stream>>>(ht, a_src1, a_dst1, asrc, adst);
    attn_kernel<<<g_attn, 256, 0, stream>>>(rowptr, csr_src, asrc, adst, ht, b1, hmid);

    // ---------- layer 2 ----------
    gemm2_mfma<<<g_gemm, 256, 0, stream>>>(hmid, W2t, ht);
    alpha_t_kernel<<<g_nh, 256, 0, stream>>>(ht, a_src2, a_dst2, asrc, adst);
    attn_kernel<<<g_attn, 256, 0, stream>>>(rowptr, csr_src, asrc, adst, ht, b2, hout);

    // ---------- output head ----------
    out_kernel<<<g_out, 256, 0, stream>>>(hout, Wo, bo, out);
}

// Round 15
// 430.490 us; speedup vs baseline: 4.5285x; 1.1085x over previous
//
#include <hip/hip_runtime.h>
#include <math.h>

#define N_NODES 50000
#define N_PAD   50016                 // padded to 32-row gemm tiles
#define N_EDGES 800000
#define E_TOT   (N_EDGES + N_NODES)   // edges + self-loops = 850000
#define F_IN    256
#define NHEAD   8
#define CH      32
#define HC      256                   // NHEAD*CH
#define OUT_C   40
#define NEG_SLOPE 0.2f
#define SCAN_BLOCKS ((N_NODES + 255) / 256)   // 196
#define G_XCVT  ((N_NODES * F_IN / 8 + 255) / 256)   // 6250
#define G_WCVT  ((HC * F_IN + 255) / 256)            // 256
#define G_WCVT2 ((HC * CH + 255) / 256)              // 32

typedef unsigned short u16;
typedef unsigned int   u32;
typedef unsigned char  u8;
typedef __attribute__((ext_vector_type(8))) short bf16x8;   // 4 VGPRs
typedef __attribute__((ext_vector_type(4))) float f32x4;
typedef __attribute__((ext_vector_type(2))) float f32x2;

__device__ __forceinline__ u16 f2bf(float f) {
    union { u32 u; float f; } x; x.f = f;
    u32 u = x.u;
    return (u16)((u + 0x7fffu + ((u >> 16) & 1u)) >> 16);   // round-nearest-even
}
__device__ __forceinline__ float bflo(u32 v) {
    union { u32 u; float f; } x; x.u = v << 16; return x.f;
}
// fp8 e4m3 encode (1 byte) / packed decode (2 floats per op) — gfx950 native
__device__ __forceinline__ u8 f2fp8(float f) {
    return (u8)(__builtin_amdgcn_cvt_pk_fp8_f32(f, f, 0, false) & 0xff);
}
// broadcast-from-head-owner within each 8-lane group (BitMode: and=0x18, or=H)
template <int H>
__device__ __forceinline__ float swz_head(float v) {
    return __int_as_float(__builtin_amdgcn_ds_swizzle(__float_as_int(v),
                                                      (H << 5) | 0x18));
}

// ht is fp8 e4m3, TRANSPOSED per node: ht8[node*256 + c*8 + hd] -> the 8
// head-values of channel c are 8 contiguous bytes (one uint2 gather in attn).

// ================= fused prep: x->bf16, W1->bf16^T, W2->bf16^T (one launch)
__global__ __launch_bounds__(256) void cvt_kernel(const float* __restrict__ x,
        u16* __restrict__ xb, const float* __restrict__ W1, u16* __restrict__ Wt,
        const float* __restrict__ W2, u16* __restrict__ W2t) {
    int b = blockIdx.x;
    if (b < G_XCVT) {
        int t = b * 256 + threadIdx.x;               // one per 8 elements
        if (t >= N_NODES * F_IN / 8) return;
        const float4* xp = (const float4*)x + (size_t)t * 2;
        float4 v0 = xp[0], v1 = xp[1];
        uint4 o;
        o.x = (u32)f2bf(v0.x) | ((u32)f2bf(v0.y) << 16);
        o.y = (u32)f2bf(v0.z) | ((u32)f2bf(v0.w) << 16);
        o.z = (u32)f2bf(v1.x) | ((u32)f2bf(v1.y) << 16);
        o.w = (u32)f2bf(v1.z) | ((u32)f2bf(v1.w) << 16);
        ((uint4*)xb)[t] = o;
    } else if (b < G_XCVT + G_WCVT) {
        int t = (b - G_XCVT) * 256 + threadIdx.x;    // 65536 total
        int n = t & 255, k = t >> 8;                 // coalesced reads
        Wt[(size_t)n * F_IN + k] = f2bf(W1[(size_t)k * HC + n]);
    } else {
        int t = (b - G_XCVT - G_WCVT) * 256 + threadIdx.x;  // 8192 total
        if (t >= HC * CH) return;
        int n = t & 255, k = t >> 8;
        W2t[(size_t)n * CH + k] = f2bf(W2[(size_t)k * HC + n]);
    }
}

// ================= GEMM1 via MFMA bf16: ht8 = fp8(x @ W1), transposed store
__global__ __launch_bounds__(256) void gemm1_mfma(const u16* __restrict__ xb,
        const u16* __restrict__ Wt, u8* __restrict__ ht8) {
    const int row0 = blockIdx.x * 32;
    const int t    = threadIdx.x;
    const int wave = t >> 6;
    const int lane = t & 63;
    const int l16  = lane & 15;
    const int quad = lane >> 4;
    const int nb   = wave * 64;

    f32x4 acc[2][4];
    #pragma unroll
    for (int m = 0; m < 2; ++m)
        #pragma unroll
        for (int n = 0; n < 4; ++n) acc[m][n] = (f32x4){0.f, 0.f, 0.f, 0.f};

    const u16* a0p = xb + (size_t)(row0 + l16) * F_IN;        // M-tile 0
    const u16* a1p = a0p + 16 * F_IN;                         // M-tile 1
    const u16* bp  = Wt + (size_t)(nb + l16) * F_IN;          // N-tile stride 16*F_IN

    #pragma unroll 1
    for (int k0 = 0; k0 < F_IN; k0 += 32) {
        const int ko = k0 + quad * 8;
        bf16x8 a0 = *(const bf16x8*)(a0p + ko);
        bf16x8 a1 = *(const bf16x8*)(a1p + ko);
        bf16x8 b0 = *(const bf16x8*)(bp + 0 * 16 * F_IN + ko);
        bf16x8 b1 = *(const bf16x8*)(bp + 1 * 16 * F_IN + ko);
        bf16x8 b2 = *(const bf16x8*)(bp + 2 * 16 * F_IN + ko);
        bf16x8 b3 = *(const bf16x8*)(bp + 3 * 16 * F_IN + ko);
        acc[0][0] = __builtin_amdgcn_mfma_f32_16x16x32_bf16(a0, b0, acc[0][0], 0, 0, 0);
        acc[0][1] = __builtin_amdgcn_mfma_f32_16x16x32_bf16(a0, b1, acc[0][1], 0, 0, 0);
        acc[0][2] = __builtin_amdgcn_mfma_f32_16x16x32_bf16(a0, b2, acc[0][2], 0, 0, 0);
        acc[0][3] = __builtin_amdgcn_mfma_f32_16x16x32_bf16(a0, b3, acc[0][3], 0, 0, 0);
        acc[1][0] = __builtin_amdgcn_mfma_f32_16x16x32_bf16(a1, b0, acc[1][0], 0, 0, 0);
        acc[1][1] = __builtin_amdgcn_mfma_f32_16x16x32_bf16(a1, b1, acc[1][1], 0, 0, 0);
        acc[1][2] = __builtin_amdgcn_mfma_f32_16x16x32_bf16(a1, b2, acc[1][2], 0, 0, 0);
        acc[1][3] = __builtin_amdgcn_mfma_f32_16x16x32_bf16(a1, b3, acc[1][3], 0, 0, 0);
    }

    #pragma unroll
    for (int m = 0; m < 2; ++m) {
        #pragma unroll
        for (int r = 0; r < 4; ++r) {
            int row = row0 + m * 16 + quad * 4 + r;
            if (row < N_NODES) {
                u8* hr = ht8 + (size_t)row * HC;
                #pragma unroll
                for (int n = 0; n < 4; ++n) {
                    int col = nb + n * 16 + l16;
                    int hd = col >> 5, cc = col & 31;
                    hr[cc * 8 + hd] = f2fp8(acc[m][n][r]);
                }
            }
        }
    }
}

// ================= GEMM2 via MFMA bf16: ht8 = fp8(hmb @ W2), K=32 single step
__global__ __launch_bounds__(256) void gemm2_mfma(const u16* __restrict__ hmb,
        const u16* __restrict__ W2t, u8* __restrict__ ht8) {
    const int row0 = blockIdx.x * 32;
    const int t    = threadIdx.x;
    const int wave = t >> 6;
    const int lane = t & 63;
    const int l16  = lane & 15;
    const int quad = lane >> 4;
    const int nb   = wave * 64;
    const int ko   = quad * 8;

    const u16* a0p = hmb + (size_t)(row0 + l16) * CH;
    const u16* a1p = a0p + 16 * CH;
    const u16* bp  = W2t + (size_t)(nb + l16) * CH;

    bf16x8 a0 = *(const bf16x8*)(a0p + ko);
    bf16x8 a1 = *(const bf16x8*)(a1p + ko);
    bf16x8 b0 = *(const bf16x8*)(bp + 0 * 16 * CH + ko);
    bf16x8 b1 = *(const bf16x8*)(bp + 1 * 16 * CH + ko);
    bf16x8 b2 = *(const bf16x8*)(bp + 2 * 16 * CH + ko);
    bf16x8 b3 = *(const bf16x8*)(bp + 3 * 16 * CH + ko);

    f32x4 z = (f32x4){0.f, 0.f, 0.f, 0.f};
    f32x4 acc[2][4];
    acc[0][0] = __builtin_amdgcn_mfma_f32_16x16x32_bf16(a0, b0, z, 0, 0, 0);
    acc[0][1] = __builtin_amdgcn_mfma_f32_16x16x32_bf16(a0, b1, z, 0, 0, 0);
    acc[0][2] = __builtin_amdgcn_mfma_f32_16x16x32_bf16(a0, b2, z, 0, 0, 0);
    acc[0][3] = __builtin_amdgcn_mfma_f32_16x16x32_bf16(a0, b3, z, 0, 0, 0);
    acc[1][0] = __builtin_amdgcn_mfma_f32_16x16x32_bf16(a1, b0, z, 0, 0, 0);
    acc[1][1] = __builtin_amdgcn_mfma_f32_16x16x32_bf16(a1, b1, z, 0, 0, 0);
    acc[1][2] = __builtin_amdgcn_mfma_f32_16x16x32_bf16(a1, b2, z, 0, 0, 0);
    acc[1][3] = __builtin_amdgcn_mfma_f32_16x16x32_bf16(a1, b3, z, 0, 0, 0);

    #pragma unroll
    for (int m = 0; m < 2; ++m) {
        #pragma unroll
        for (int r = 0; r < 4; ++r) {
            int row = row0 + m * 16 + quad * 4 + r;
            if (row < N_NODES) {
                u8* hr = ht8 + (size_t)row * HC;
                #pragma unroll
                for (int n = 0; n < 4; ++n) {
                    int col = nb + n * 16 + l16;
                    int hd = col >> 5, cc = col & 31;
                    hr[cc * 8 + hd] = f2fp8(acc[m][n][r]);
                }
            }
        }
    }
}

// ================= alpha from fp8 ht: thread = node, a-vectors in LDS
__global__ __launch_bounds__(256) void alpha_t_kernel(const u8* __restrict__ ht8,
        const float* __restrict__ a_src, const float* __restrict__ a_dst,
        float* __restrict__ asrc, float* __restrict__ adst) {
    __shared__ float sas[HC], sad[HC];
    for (int i = threadIdx.x; i < HC; i += 256) {
        sas[i] = a_src[i];
        sad[i] = a_dst[i];
    }
    __syncthreads();
    int node = blockIdx.x * 256 + threadIdx.x;
    if (node >= N_NODES) return;
    const uint2* hp = (const uint2*)(ht8 + (size_t)node * HC);   // 32 uint2
    float s1[NHEAD], s2[NHEAD];
    #pragma unroll
    for (int h = 0; h < NHEAD; ++h) { s1[h] = 0.f; s2[h] = 0.f; }
    #pragma unroll 4
    for (int c = 0; c < CH; ++c) {
        uint2 v = hp[c];
        f32x2 p01 = __builtin_amdgcn_cvt_pk_f32_fp8(v.x, false);
        f32x2 p23 = __builtin_amdgcn_cvt_pk_f32_fp8(v.x, true);
        f32x2 p45 = __builtin_amdgcn_cvt_pk_f32_fp8(v.y, false);
        f32x2 p67 = __builtin_amdgcn_cvt_pk_f32_fp8(v.y, true);
        float f[NHEAD] = {p01.x, p01.y, p23.x, p23.y, p45.x, p45.y, p67.x, p67.y};
        #pragma unroll
        for (int h = 0; h < NHEAD; ++h) {
            s1[h] += f[h] * sas[h * CH + c];   // same addr all lanes -> broadcast
            s2[h] += f[h] * sad[h * CH + c];
        }
    }
    float4* o1 = (float4*)(asrc + (size_t)node * NHEAD);
    float4* o2 = (float4*)(adst + (size_t)node * NHEAD);
    o1[0] = make_float4(s1[0], s1[1], s1[2], s1[3]);
    o1[1] = make_float4(s1[4], s1[5], s1[6], s1[7]);
    o2[0] = make_float4(s2[0], s2[1], s2[2], s2[3]);
    o2[1] = make_float4(s2[4], s2[5], s2[6], s2[7]);
}

// ================= CSR build =================
__global__ __launch_bounds__(256) void deg_kernel(const int* __restrict__ ei,
        int* __restrict__ deg) {
    int j = blockIdx.x * 256 + threadIdx.x;
    if (j >= E_TOT) return;
    int dst = (j < N_EDGES) ? ei[N_EDGES + j] : (j - N_EDGES);
    atomicAdd(&deg[dst], 1);
}

__device__ __forceinline__ int wave_incl_scan(int v, int lane) {
    #pragma unroll
    for (int d = 1; d < 64; d <<= 1) {
        int u = __shfl_up(v, d, 64);
        if (lane >= d) v += u;
    }
    return v;
}

__global__ __launch_bounds__(256) void scan1_kernel(const int* __restrict__ deg,
        int* __restrict__ rowptr, int* __restrict__ partials) {
    const int t    = blockIdx.x * 256 + threadIdx.x;
    const int lane = threadIdx.x & 63;
    const int wid  = threadIdx.x >> 6;
    int v = (t < N_NODES) ? deg[t] : 0;
    int inc = wave_incl_scan(v, lane);
    __shared__ int wtot[4];
    if (lane == 63) wtot[wid] = inc;
    __syncthreads();
    int woff = 0;
    #pragma unroll
    for (int i = 0; i < 4; ++i) woff += (i < wid) ? wtot[i] : 0;
    if (t < N_NODES) rowptr[t] = inc - v + woff;      // block-local exclusive
    if (threadIdx.x == 255) partials[blockIdx.x] = woff + inc;  // block total
}

__global__ __launch_bounds__(256) void scan2_kernel(int* __restrict__ partials) {
    const int t    = threadIdx.x;
    const int lane = t & 63;
    const int wid  = t >> 6;
    int v = (t < SCAN_BLOCKS) ? partials[t] : 0;
    int inc = wave_incl_scan(v, lane);
    __shared__ int wtot[4];
    if (lane == 63) wtot[wid] = inc;
    __syncthreads();
    int woff = 0;
    #pragma unroll
    for (int i = 0; i < 4; ++i) woff += (i < wid) ? wtot[i] : 0;
    __syncthreads();
    if (t < SCAN_BLOCKS) partials[t] = inc - v + woff;
}

__global__ __launch_bounds__(256) void scan3_kernel(int* __restrict__ rowptr,
        int* __restrict__ cursor, const int* __restrict__ partials) {
    const int t = blockIdx.x * 256 + threadIdx.x;
    if (t < N_NODES) {
        int v = rowptr[t] + partials[blockIdx.x];
        rowptr[t] = v;
        cursor[t] = v;
    } else if (t == N_NODES) {
        rowptr[N_NODES] = E_TOT;
    }
}

__global__ __launch_bounds__(256) void scatter_kernel(const int* __restrict__ ei,
        int* __restrict__ cursor, int* __restrict__ csr_src) {
    int j = blockIdx.x * 256 + threadIdx.x;
    if (j >= E_TOT) return;
    int src, dst;
    if (j < N_EDGES) { src = ei[j]; dst = ei[N_EDGES + j]; }
    else             { src = j - N_EDGES; dst = src; }
    int pos = atomicAdd(&cursor[dst], 1);
    csr_src[pos] = src;
}

// ================= fused attention: softmax + aggregate in ONE pass
// fp8 ht (r15): per-edge payload 256B instead of 512B — attn was BW-bound at
// FETCH 220MB / 3TB/s (r14). Depth-1 prefetch + head-owner swizzle kept.
__global__ __launch_bounds__(256) void attn_kernel(const int* __restrict__ rowptr,
        const int* __restrict__ csr_src, const float* __restrict__ asrc,
        const float* __restrict__ adst, const u8* __restrict__ ht8,
        const float* __restrict__ b, u16* __restrict__ out) {
    int t = blockIdx.x * 256 + threadIdx.x;
    if (t >= N_NODES * CH) return;
    int dst = t >> 5;
    int c   = t & 31;
    int hown = c & 7;                               // this lane's owned head
    const float ad_own = adst[dst * NHEAD + hown];
    const uint2* H8 = (const uint2*)ht8;  // row = 32 uint2; lane c reads uint2 #c

    float acc[NHEAD];
    #pragma unroll
    for (int h = 0; h < NHEAD; ++h) acc[h] = 0.f;
    float wsum_own = 0.f;

    int p0 = rowptr[dst], p1 = rowptr[dst + 1];
    // prologue: every dst has >=1 edge (self-loop)
    int   src0 = csr_src[p0];
    float as_n = asrc[src0 * NHEAD + hown];
    uint2 hv_n = H8[(size_t)src0 * 32 + c];
    for (int p = p0; p < p1; ++p) {
        float as_c = as_n;
        uint2 hv_c = hv_n;
        int pn = p + 1;
        if (pn < p1) {                              // prefetch next edge
            int srcn = csr_src[pn];
            as_n = asrc[srcn * NHEAD + hown];
            hv_n = H8[(size_t)srcn * 32 + c];
        }
        float e = as_c + ad_own;
        e = e > 0.f ? e : NEG_SLOPE * e;
        float w = __expf(e);                        // ONE exp per lane
        wsum_own += w;
        float w0 = swz_head<0>(w), w1 = swz_head<1>(w);
        float w2 = swz_head<2>(w), w3 = swz_head<3>(w);
        float w4 = swz_head<4>(w), w5 = swz_head<5>(w);
        float w6 = swz_head<6>(w), w7 = swz_head<7>(w);
        f32x2 p01 = __builtin_amdgcn_cvt_pk_f32_fp8(hv_c.x, false);
        f32x2 p23 = __builtin_amdgcn_cvt_pk_f32_fp8(hv_c.x, true);
        f32x2 p45 = __builtin_amdgcn_cvt_pk_f32_fp8(hv_c.y, false);
        f32x2 p67 = __builtin_amdgcn_cvt_pk_f32_fp8(hv_c.y, true);
        acc[0] += w0 * p01.x;  acc[1] += w1 * p01.y;
        acc[2] += w2 * p23.x;  acc[3] += w3 * p23.y;
        acc[4] += w4 * p45.x;  acc[5] += w5 * p45.y;
        acc[6] += w6 * p67.x;  acc[7] += w7 * p67.y;
    }
    float val = 0.f;
    val += acc[0] / swz_head<0>(wsum_own);
    val += acc[1] / swz_head<1>(wsum_own);
    val += acc[2] / swz_head<2>(wsum_own);
    val += acc[3] / swz_head<3>(wsum_own);
    val += acc[4] / swz_head<4>(wsum_own);
    val += acc[5] / swz_head<5>(wsum_own);
    val += acc[6] / swz_head<6>(wsum_own);
    val += acc[7] / swz_head<7>(wsum_own);
    val = val * 0.125f + b[c];
    val = val > 0.f ? val : (__expf(val) - 1.f);
    out[t] = f2bf(val);
}

// ================= output head: 4 nodes/block (1 wave each), log_softmax
__global__ __launch_bounds__(256) void out_kernel(const u16* __restrict__ hf,
        const float* __restrict__ Wo, const float* __restrict__ bo,
        float* __restrict__ out) {
    const int wave = threadIdx.x >> 6;
    const int lane = threadIdx.x & 63;
    const int n    = blockIdx.x * 4 + wave;
    __shared__ float hs[4][CH];
    if (n < N_NODES && lane < CH) hs[wave][lane] = bflo((u32)hf[n * CH + lane]);
    __syncthreads();
    if (n >= N_NODES) return;
    float logit = -INFINITY;
    if (lane < OUT_C) {
        float a = bo[lane];
        #pragma unroll
        for (int k = 0; k < CH; ++k) a += hs[wave][k] * Wo[k * OUT_C + lane];
        logit = a;
    }
    float m = logit;
    #pragma unroll
    for (int off = 32; off; off >>= 1) m = fmaxf(m, __shfl_xor(m, off, 64));
    float ex = (lane < OUT_C) ? __expf(logit - m) : 0.f;
    float ssum = ex;
    #pragma unroll
    for (int off = 32; off; off >>= 1) ssum += __shfl_xor(ssum, off, 64);
    if (lane < OUT_C) out[(size_t)n * OUT_C + lane] = logit - m - __logf(ssum);
}

extern "C" void kernel_launch(void* const* d_in, const int* in_sizes, int n_in,
                              void* d_out, int out_size, void* d_ws, size_t ws_size,
                              hipStream_t stream) {
    const float* x      = (const float*)d_in[0];
    const int*   ei     = (const int*)  d_in[1];
    const float* W1     = (const float*)d_in[2];
    const float* a_src1 = (const float*)d_in[3];
    const float* a_dst1 = (const float*)d_in[4];
    const float* b1     = (const float*)d_in[5];
    const float* W2     = (const float*)d_in[6];
    const float* a_src2 = (const float*)d_in[7];
    const float* a_dst2 = (const float*)d_in[8];
    const float* b2     = (const float*)d_in[9];
    const float* Wo     = (const float*)d_in[10];
    const float* bo     = (const float*)d_in[11];
    float* out = (float*)d_out;

    // workspace carve-up (256B-aligned)
    char* ws = (char*)d_ws;
    size_t off = 0;
    auto carve = [&](size_t bytes) { char* p = ws + off; off += (bytes + 255) & ~(size_t)255; return p; };
    u8*    ht8     = (u8*)   carve((size_t)N_NODES * HC);          // 12.8 MB (fp8, transposed)
    u16*   xb      = (u16*)  carve((size_t)N_PAD * F_IN * 2);      // 25.6 MB (bf16 x, padded)
    u16*   Wt      = (u16*)  carve((size_t)HC * F_IN * 2);         // 128 KB (bf16 W1^T)
    u16*   W2t     = (u16*)  carve((size_t)HC * CH * 2);           // 16 KB (bf16 W2^T)
    float* asrc    = (float*)carve((size_t)N_NODES * NHEAD * 4);   // 1.6 MB
    float* adst    = (float*)carve((size_t)N_NODES * NHEAD * 4);
    u16*   hmid    = (u16*)  carve((size_t)N_PAD * CH * 2);        // 3.2 MB (bf16)
    u16*   hout    = (u16*)  carve((size_t)N_NODES * CH * 2);      // 3.2 MB (bf16)
    int*   deg     = (int*)  carve((size_t)N_NODES * 4);
    int*   rowptr  = (int*)  carve((size_t)(N_NODES + 1) * 4);
    int*   cursor  = (int*)  carve((size_t)N_NODES * 4);
    int*   csr_src = (int*)  carve((size_t)E_TOT * 4);             // 3.4 MB
    int*   partials= (int*)  carve((size_t)SCAN_BLOCKS * 4);

    const int g_cvt   = G_XCVT + G_WCVT + G_WCVT2;           // 6538
    const int g_gemm  = (N_NODES + 31) / 32;                 // 1563
    const int g_node  = (N_NODES + 255) / 256;               // 196
    const int g_edge  = (E_TOT + 255) / 256;                 // 3321
    const int g_attn  = (N_NODES * CH + 255) / 256;          // 6250
    const int g_out   = (N_NODES + 3) / 4;                   // 12500

    // ---------- prep + CSR build ----------
    cvt_kernel<<<g_cvt, 256, 0, stream>>>(x, xb, W1, Wt, W2, W2t);
    (void)hipMemsetAsync(deg, 0, (size_t)N_NODES * 4, stream);
    deg_kernel<<<g_edge, 256, 0, stream>>>(ei, deg);
    scan1_kernel<<<SCAN_BLOCKS, 256, 0, stream>>>(deg, rowptr, partials);
    scan2_kernel<<<1, 256, 0, stream>>>(partials);
    scan3_kernel<<<SCAN_BLOCKS, 256, 0, stream>>>(rowptr, cursor, partials);
    scatter_kernel<<<g_edge, 256, 0, stream>>>(ei, cursor, csr_src);

    // ---------- layer 1 ----------
    gemm1_mfma<<<g_gemm, 256, 0, stream>>>(xb, Wt, ht8);
    alpha_t_kernel<<<g_node, 256, 0, stream>>>(ht8, a_src1, a_dst1, asrc, adst);
    attn_kernel<<<g_attn, 256, 0, stream>>>(rowptr, csr_src, asrc, adst, ht8, b1, hmid);

    // ---------- layer 2 ----------
    gemm2_mfma<<<g_gemm, 256, 0, stream>>>(hmid, W2t, ht8);
    alpha_t_kernel<<<g_node, 256, 0, stream>>>(ht8, a_src2, a_dst2, asrc, adst);
    attn_kernel<<<g_attn, 256, 0, stream>>>(rowptr, csr_src, asrc, adst, ht8, b2, hout);

    // ---------- output head ----------
    out_kernel<<<g_out, 256, 0, stream>>>(hout, Wo, bo, out);
}